// Round 1
// baseline (1671.970 us; speedup 1.0000x reference)
//
#include <hip/hip_runtime.h>
#include <hip/hip_bf16.h>
#include <cstdio>

// ---------------------------------------------------------------------------
// DeltaNet forward, MI355X round 1: all-f32 correctness-first baseline.
// Pipeline:
//   gemm128 x3 (q/k/v proj) + beta_sigmoid
//   conv4_silu x3  -> head-major q,k,v
//   prep_qkv       -> l2norm q,k; kb=kn*beta; vb=v*beta
//   chunk_prep     -> A=tril(kb.kn^T,-1), T=inv(I+A) (exact fwd-subst),
//                     attn=tril(qn.kn^T), w=T@kb, u=T@vb
//   delta_chain    -> serial over 64 chunks, S[256x8] per block in regs,
//                     u2 (overwrites u) + o1=qi@S ; 256 blocks (b,h,dv/8)
//   delta_attn_add -> delta = o1 + attn@u2   (parallel over chunks)
//   fir_conv       -> 63-tap + 3-tap causal depthwise over v
//   build_gate_in, gemm128(mlp1,gelu), mlp2_gates(softmax)
//   combine_norm (RMSNorm), gemm128 (output proj)
// Workspace: 46,874,624 floats = 187.5 MB, heavy slot reuse (see offsets).
// ---------------------------------------------------------------------------

#define DEVI __device__ __forceinline__

constexpr int Ls = 2048, NH = 4;
constexpr int NCh = 64;   // chunks of 32

// workspace offsets (floats)
constexpr size_t off_xq   = 0;         // x@Wq -> later qn
constexpr size_t off_xk   = 4194304;   // x@Wk -> later kn -> later o
constexpr size_t off_xv   = 8388608;   // x@Wv -> later vb -> u -> u2
constexpr size_t off_q    = 12582912;  // q -> later kb -> later delta (o1)
constexpr size_t off_k    = 16777216;  // k -> later w
constexpr size_t off_v    = 20971520;  // v (alive to the end)
constexpr size_t off_beta = 25165824;  // [bh][l] 16384
constexpr size_t off_attn = 25182208;  // [bh][cc][32][32] 524288
constexpr size_t off_firs = 25706496;  // token-major [m][h][d]
constexpr size_t off_firl = 29900800;
constexpr size_t off_gin  = 34095104;  // [m][1056]
constexpr size_t off_mlph = 38420480;  // [m][2048]
constexpr size_t off_gates= 46809088;  // [m][16]
constexpr size_t WS_FLOATS = 46874624;

DEVI float dot4(float4 a, float4 b) {
  return a.x*b.x + a.y*b.y + a.z*b.z + a.w*b.w;
}
DEVI float sigmoidf_(float x) { return 1.f / (1.f + expf(-x)); }
DEVI float siluf_(float x) { return x / (1.f + expf(-x)); }
DEVI float geluf_(float x) { return 0.5f * x * (1.f + erff(x * 0.7071067811865476f)); }

// ---------------- generic f32 GEMM: C[M,N] = A[M,K] @ W[K,N] ---------------
// tile 128x128, BK=16, 256 threads, 8x8 per thread. act: 0 none, 1 bias+gelu.
__global__ __launch_bounds__(256) void gemm128(
    const float* __restrict__ A, const float* __restrict__ W,
    float* __restrict__ C, int Mq, int Nq, int Kq,
    const float* __restrict__ bias, int act)
{
  __shared__ float As[16][132];   // transposed: As[kk][m]
  __shared__ float Ws[16][132];   // Ws[kk][n]
  int t = threadIdx.x;
  int m0 = blockIdx.y * 128, n0 = blockIdx.x * 128;
  int tx = t & 15, ty = t >> 4;
  float acc[8][8];
#pragma unroll
  for (int r = 0; r < 8; ++r)
#pragma unroll
    for (int c = 0; c < 8; ++c) acc[r][c] = 0.f;

  for (int kt = 0; kt < Kq; kt += 16) {
#pragma unroll
    for (int qq = 0; qq < 2; ++qq) {
      int s = t * 2 + qq;
      int row = s >> 2, c4 = s & 3;
      float4 av = *(const float4*)(A + (size_t)(m0 + row) * Kq + kt + c4 * 4);
      As[c4*4+0][row] = av.x; As[c4*4+1][row] = av.y;
      As[c4*4+2][row] = av.z; As[c4*4+3][row] = av.w;
      int rw = s >> 5, cw = s & 31;
      *(float4*)&Ws[rw][cw*4] = *(const float4*)(W + (size_t)(kt + rw) * Nq + n0 + cw * 4);
    }
    __syncthreads();
#pragma unroll
    for (int kk = 0; kk < 16; ++kk) {
      float4 a0 = *(float4*)&As[kk][ty*8], a1 = *(float4*)&As[kk][ty*8+4];
      float4 b0 = *(float4*)&Ws[kk][tx*8], b1 = *(float4*)&Ws[kk][tx*8+4];
      float ar[8] = {a0.x,a0.y,a0.z,a0.w,a1.x,a1.y,a1.z,a1.w};
      float br[8] = {b0.x,b0.y,b0.z,b0.w,b1.x,b1.y,b1.z,b1.w};
#pragma unroll
      for (int r = 0; r < 8; ++r)
#pragma unroll
        for (int c = 0; c < 8; ++c) acc[r][c] = fmaf(ar[r], br[c], acc[r][c]);
    }
    __syncthreads();
  }
#pragma unroll
  for (int r = 0; r < 8; ++r) {
    size_t rowoff = (size_t)(m0 + ty*8 + r) * Nq + n0 + tx*8;
    float v[8];
#pragma unroll
    for (int c = 0; c < 8; ++c) v[c] = acc[r][c];
    if (act == 1) {
#pragma unroll
      for (int c = 0; c < 8; ++c) v[c] = geluf_(v[c] + bias[n0 + tx*8 + c]);
    }
    *(float4*)(C + rowoff)     = make_float4(v[0], v[1], v[2], v[3]);
    *(float4*)(C + rowoff + 4) = make_float4(v[4], v[5], v[6], v[7]);
  }
}

// ---------------- beta = sigmoid(x @ Wb), head-major [bh][l] ---------------
__global__ __launch_bounds__(256) void beta_sigmoid(
    const float* __restrict__ x, const float* __restrict__ Wb,
    float* __restrict__ beta)
{
  int mtok = blockIdx.x, t = threadIdx.x;
  int b = mtok >> 11, l = mtok & 2047;
  float a0 = 0, a1 = 0, a2 = 0, a3 = 0;
  for (int k = t; k < 1024; k += 256) {
    float xv = x[(size_t)mtok * 1024 + k];
    float4 w4 = *(const float4*)(Wb + k * 4);
    a0 = fmaf(xv, w4.x, a0); a1 = fmaf(xv, w4.y, a1);
    a2 = fmaf(xv, w4.z, a2); a3 = fmaf(xv, w4.w, a3);
  }
#pragma unroll
  for (int off = 32; off; off >>= 1) {
    a0 += __shfl_down(a0, off); a1 += __shfl_down(a1, off);
    a2 += __shfl_down(a2, off); a3 += __shfl_down(a3, off);
  }
  __shared__ float red[4][4];
  int w = t >> 6;
  if ((t & 63) == 0) { red[w][0] = a0; red[w][1] = a1; red[w][2] = a2; red[w][3] = a3; }
  __syncthreads();
  if (t < 4) {
    float s = red[0][t] + red[1][t] + red[2][t] + red[3][t];
    beta[((size_t)(b * NH + t)) * Ls + l] = sigmoidf_(s);
  }
}

// ------- causal depthwise conv k=4 + silu; [b,l,c] -> head-major [bh,l,d] ---
__global__ __launch_bounds__(256) void conv4_silu(
    const float* __restrict__ xin, const float* __restrict__ wt,
    float* __restrict__ out)
{
  int gid = blockIdx.x * 256 + threadIdx.x;   // over B*L*1024
  int c = gid & 1023;
  int l = (gid >> 10) & 2047;
  int b = gid >> 21;
  float4 w4 = *(const float4*)(wt + c * 4);
  float wj[4] = {w4.x, w4.y, w4.z, w4.w};
  const float* xp = xin + ((size_t)b * Ls) * 1024 + c;
  float acc = 0.f;
#pragma unroll
  for (int j = 0; j < 4; ++j) {
    int ls = l - 3 + j;
    float xv = (ls >= 0) ? xp[(size_t)ls * 1024] : 0.f;
    acc = fmaf(wj[j], xv, acc);
  }
  float y = siluf_(acc);
  int h = c >> 8, d = c & 255;
  out[(((size_t)(b * NH + h)) * Ls + l) * 256 + d] = y;
}

// ------- l2norm q,k; kb = kn*beta; vb = v*beta (per (bh,l) block) ----------
__global__ __launch_bounds__(256) void prep_qkv(
    const float* __restrict__ q, const float* __restrict__ k,
    const float* __restrict__ v, const float* __restrict__ beta,
    float* __restrict__ qn, float* __restrict__ kn,
    float* __restrict__ kb, float* __restrict__ vb)
{
  int i = blockIdx.x;          // (b*NH+h)*Ls + l
  int t = threadIdx.x;
  size_t base = (size_t)i * 256 + t;
  float qv = q[base], kv = k[base], vv = v[base];
  float sq = qv * qv, sk = kv * kv;
#pragma unroll
  for (int off = 32; off; off >>= 1) {
    sq += __shfl_down(sq, off);
    sk += __shfl_down(sk, off);
  }
  __shared__ float rq_[4], rk_[4];
  int w = t >> 6;
  if ((t & 63) == 0) { rq_[w] = sq; rk_[w] = sk; }
  __syncthreads();
  sq = rq_[0] + rq_[1] + rq_[2] + rq_[3];
  sk = rk_[0] + rk_[1] + rk_[2] + rk_[3];
  float rq = rsqrtf(sq + 1e-6f), rk = rsqrtf(sk + 1e-6f);
  float bt = beta[i];
  qn[base] = qv * rq;
  kn[base] = kv * rk;
  kb[base] = kv * rk * bt;
  vb[base] = vv * bt;
}

// ------- per (b,h,chunk): A, T=inv(I+A), attn, w=T@kb, u=T@vb --------------
__global__ __launch_bounds__(256) void chunk_prep(
    const float* __restrict__ kb, const float* __restrict__ kn,
    const float* __restrict__ qn, const float* __restrict__ vb,
    float* __restrict__ attn_g, float* __restrict__ w_out,
    float* __restrict__ u_out)
{
  __shared__ float kbs[32][260], kns[32][260], bufs[32][260];
  __shared__ float Am[32][33], Tm[32][33];
  int t = threadIdx.x;
  int cc = blockIdx.x & 63, bh = blockIdx.x >> 6;
  size_t gbase = ((size_t)bh * Ls + cc * 32) * 256;
#pragma unroll
  for (int r = 0; r < 8; ++r) {
    int s = r * 256 + t; int row = s >> 6, c4 = (s & 63) * 4;
    *(float4*)&kbs[row][c4]  = *(const float4*)(kb + gbase + row * 256 + c4);
    *(float4*)&kns[row][c4]  = *(const float4*)(kn + gbase + row * 256 + c4);
    *(float4*)&bufs[row][c4] = *(const float4*)(qn + gbase + row * 256 + c4);
  }
  __syncthreads();
  float* ag = attn_g + ((size_t)bh * 64 + cc) * 1024;
#pragma unroll
  for (int p = 0; p < 4; ++p) {
    int pair = p * 256 + t, i = pair >> 5, j = pair & 31;
    float aA = 0.f, aQ = 0.f;
#pragma unroll 8
    for (int kk = 0; kk < 256; kk += 4) {
      float4 kf = *(float4*)&kns[j][kk];
      float4 bf = *(float4*)&kbs[i][kk];
      float4 qf = *(float4*)&bufs[i][kk];
      aA += dot4(bf, kf);
      aQ += dot4(qf, kf);
    }
    Am[i][j] = (j < i) ? aA : 0.f;
    ag[i * 32 + j] = (j <= i) ? aQ : 0.f;
  }
  __syncthreads();
  if (t < 32) {
    for (int i2 = 0; i2 < 32; ++i2) Tm[i2][t] = (i2 == t) ? 1.f : 0.f;
  }
  __syncthreads();
  for (int i2 = 1; i2 < 32; ++i2) {          // forward substitution (exact)
    if (t < i2) {
      float s = 0.f;
      for (int m2 = t; m2 < i2; ++m2) s = fmaf(Am[i2][m2], Tm[m2][t], s);
      Tm[i2][t] = -s;
    }
    __syncthreads();
  }
#pragma unroll
  for (int r = 0; r < 8; ++r) {              // reload bufs with vb
    int s = r * 256 + t; int row = s >> 6, c4 = (s & 63) * 4;
    *(float4*)&bufs[row][c4] = *(const float4*)(vb + gbase + row * 256 + c4);
  }
  __syncthreads();
  int d4 = (t & 63) * 4, i8 = (t >> 6) * 8;
#pragma unroll
  for (int r = 0; r < 8; ++r) {
    int i = i8 + r;
    float4 wa = make_float4(0,0,0,0), ua = make_float4(0,0,0,0);
#pragma unroll
    for (int m2 = 0; m2 < 32; ++m2) {
      float tv = Tm[i][m2];
      float4 kbf = *(float4*)&kbs[m2][d4];
      float4 vbf = *(float4*)&bufs[m2][d4];
      wa.x = fmaf(tv, kbf.x, wa.x); wa.y = fmaf(tv, kbf.y, wa.y);
      wa.z = fmaf(tv, kbf.z, wa.z); wa.w = fmaf(tv, kbf.w, wa.w);
      ua.x = fmaf(tv, vbf.x, ua.x); ua.y = fmaf(tv, vbf.y, ua.y);
      ua.z = fmaf(tv, vbf.z, ua.z); ua.w = fmaf(tv, vbf.w, ua.w);
    }
    *(float4*)(w_out + gbase + i * 256 + d4) = wa;
    *(float4*)(u_out + gbase + i * 256 + d4) = ua;
  }
}

// ------- serial chunk scan: 256 blocks = (b,h) x 32 dv-slices of 8 ---------
// S[dk=256][8] : thread t holds row dk=t in regs, mirrored transposed in LDS.
// per chunk: u2 = u - w@S (stored over u), o1 = q@S (stored to delta slot),
//            S += k^T @ u2.
__global__ __launch_bounds__(256) void delta_chain(
    const float* __restrict__ kn, const float* __restrict__ w_g,
    const float* __restrict__ qn, float* __restrict__ u_g,
    float* __restrict__ o1_g)
{
  __shared__ float wis[32][264], qis[32][264];
  __shared__ float St[8][264];     // St[jj][dk] = S[dk][j0+jj]
  __shared__ float u2s[32][8];
  int t = threadIdx.x;
  int js = blockIdx.x & 31, bh = blockIdx.x >> 5;
  int j0 = js * 8;
  int b = bh >> 2, h = bh & 3;
  const float* knp = kn + (size_t)bh * Ls * 256;
  const float* wp  = w_g + (size_t)bh * Ls * 256;
  const float* qp  = qn + (size_t)bh * Ls * 256;
  float* up = u_g + (size_t)bh * Ls * 256;
  float Sreg[8];
#pragma unroll
  for (int jj = 0; jj < 8; ++jj) { Sreg[jj] = 0.f; St[jj][t] = 0.f; }
  __syncthreads();
  int ui = t >> 3, uj = t & 7;
  for (int cc = 0; cc < NCh; ++cc) {
    size_t cb = (size_t)cc * 32 * 256;
#pragma unroll
    for (int r = 0; r < 8; ++r) {
      int s = r * 256 + t; int row = s >> 6, c4 = (s & 63) * 4;
      *(float4*)&wis[row][c4] = *(const float4*)(wp + cb + row * 256 + c4);
      *(float4*)&qis[row][c4] = *(const float4*)(qp + cb + row * 256 + c4);
    }
    float kcol[32];
#pragma unroll
    for (int i = 0; i < 32; ++i) kcol[i] = knp[cb + i * 256 + t];
    __syncthreads();
    // u2 and o1 for this slice: row-dots against transposed S
    float accU = up[cb + ui * 256 + j0 + uj];
    float accO = 0.f;
#pragma unroll 8
    for (int kk = 0; kk < 256; kk += 4) {
      float4 s4 = *(float4*)&St[uj][kk];
      float4 w4 = *(float4*)&wis[ui][kk];
      float4 q4 = *(float4*)&qis[ui][kk];
      accU -= dot4(w4, s4);
      accO += dot4(q4, s4);
    }
    u2s[ui][uj] = accU;
    up[cb + ui * 256 + j0 + uj] = accU;          // persist u2 for attn pass
    {
      int l = cc * 32 + ui;
      o1_g[(((size_t)b * Ls + l) * NH + h) * 256 + j0 + uj] = accO;
    }
    __syncthreads();
    // S update: S[t][jj] += sum_i kn[i][t] * u2[i][jj]
#pragma unroll
    for (int i = 0; i < 32; ++i) {
      float f = kcol[i];
      float4 u20 = *(float4*)&u2s[i][0];
      float4 u21 = *(float4*)&u2s[i][4];
      Sreg[0] = fmaf(f, u20.x, Sreg[0]); Sreg[1] = fmaf(f, u20.y, Sreg[1]);
      Sreg[2] = fmaf(f, u20.z, Sreg[2]); Sreg[3] = fmaf(f, u20.w, Sreg[3]);
      Sreg[4] = fmaf(f, u21.x, Sreg[4]); Sreg[5] = fmaf(f, u21.y, Sreg[5]);
      Sreg[6] = fmaf(f, u21.z, Sreg[6]); Sreg[7] = fmaf(f, u21.w, Sreg[7]);
    }
#pragma unroll
    for (int jj = 0; jj < 8; ++jj) St[jj][t] = Sreg[jj];
    __syncthreads();
  }
}

// ------- delta += attn @ u2, parallel over (bh, chunk) ---------------------
__global__ __launch_bounds__(256) void delta_attn_add(
    const float* __restrict__ attn_g, const float* __restrict__ u2_g,
    float* __restrict__ delta)
{
  __shared__ float u2s[32][260];
  __shared__ float at[32][36];
  int t = threadIdx.x;
  int cc = blockIdx.x & 63, bh = blockIdx.x >> 6;
  int b = bh >> 2, h = bh & 3;
  size_t gbase = ((size_t)bh * Ls + cc * 32) * 256;
#pragma unroll
  for (int r = 0; r < 8; ++r) {
    int s = r * 256 + t; int row = s >> 6, c4 = (s & 63) * 4;
    *(float4*)&u2s[row][c4] = *(const float4*)(u2_g + gbase + row * 256 + c4);
  }
  *(float4*)&at[t >> 3][(t & 7) * 4] =
      *(const float4*)(attn_g + ((size_t)bh * 64 + cc) * 1024 + t * 4);
  __syncthreads();
  int d4 = (t & 63) * 4, i8 = (t >> 6) * 8;
#pragma unroll
  for (int r = 0; r < 8; ++r) {
    int i = i8 + r;
    int l = cc * 32 + i;
    size_t ob = (((size_t)b * Ls + l) * NH + h) * 256 + d4;
    float4 acc = *(float4*)(delta + ob);
#pragma unroll
    for (int m = 0; m < 32; ++m) {
      float av = at[i][m];
      float4 uf = *(float4*)&u2s[m][d4];
      acc.x = fmaf(av, uf.x, acc.x); acc.y = fmaf(av, uf.y, acc.y);
      acc.z = fmaf(av, uf.z, acc.z); acc.w = fmaf(av, uf.w, acc.w);
    }
    *(float4*)(delta + ob) = acc;
  }
}

// ------- FIR 63-tap + 3-tap causal depthwise over v (head-major in) --------
// outputs token-major [m][h][d]; taps in registers, 8 l per thread.
__global__ __launch_bounds__(256) void fir_conv(
    const float* __restrict__ v, const float* __restrict__ wlg,
    const float* __restrict__ wsg, float* __restrict__ firl,
    float* __restrict__ firs)
{
  __shared__ float vt[256][71];
  int t = threadIdx.x;
  int lt = blockIdx.x & 255;         // L/8
  int bh = blockIdx.x >> 8;
  int b = bh >> 2, h = bh & 3;
  int l0 = lt * 8;
  const float* vp = v + (size_t)bh * Ls * 256;
  for (int r = 0; r < 70; ++r) {
    int ls = l0 - 62 + r;
    vt[t][r] = (ls >= 0) ? vp[(size_t)ls * 256 + t] : 0.f;
  }
  float TL[63], TS3[3];
#pragma unroll
  for (int j = 0; j < 63; ++j) TL[j] = wlg[((size_t)h * 256 + t) * 63 + j];
#pragma unroll
  for (int j = 0; j < 3; ++j) TS3[j] = wsg[((size_t)h * 256 + t) * 3 + j];
  __syncthreads();
  float aL[8] = {0,0,0,0,0,0,0,0}, aS[8] = {0,0,0,0,0,0,0,0};
#pragma unroll
  for (int r = 0; r < 70; ++r) {
    float vm = vt[t][r];
#pragma unroll
    for (int p = 0; p < 8; ++p) {
      int jl = r - p;
      if (jl >= 0 && jl < 63) aL[p] = fmaf(vm, TL[jl], aL[p]);
      int jssrc = r - 60 - p;
      if (jssrc >= 0 && jssrc < 3) aS[p] = fmaf(vm, TS3[jssrc], aS[p]);
    }
  }
#pragma unroll
  for (int p = 0; p < 8; ++p) {
    int l = l0 + p;
    size_t ob = (((size_t)b * Ls + l) * NH + h) * 256 + t;
    firl[ob] = aL[p];
    firs[ob] = aS[p];
  }
}

// ------- gate_in = [x | stats(firs) | stats(firl) | stats(delta) | stats(v)]
__global__ __launch_bounds__(256) void build_gate_in(
    const float* __restrict__ x, const float* __restrict__ firs,
    const float* __restrict__ firl, const float* __restrict__ delta,
    const float* __restrict__ v, float* __restrict__ gin)
{
  int mtok = blockIdx.x, t = threadIdx.x;
  int b = mtok >> 11, l = mtok & 2047;
  *(float4*)(gin + (size_t)mtok * 1056 + t * 4) =
      *(const float4*)(x + (size_t)mtok * 1024 + t * 4);
  int w = t >> 6, lane = t & 63;
  for (int br = 0; br < 4; ++br) {
    float s = 0.f, s2 = 0.f;
#pragma unroll
    for (int r = 0; r < 4; ++r) {
      int d = lane + r * 64;
      float val;
      if (br == 0)      val = firs [(size_t)mtok * 1024 + w * 256 + d];
      else if (br == 1) val = firl [(size_t)mtok * 1024 + w * 256 + d];
      else if (br == 2) val = delta[(size_t)mtok * 1024 + w * 256 + d];
      else              val = v[(((size_t)(b * NH + w)) * Ls + l) * 256 + d];
      s += val; s2 = fmaf(val, val, s2);
    }
#pragma unroll
    for (int off = 32; off; off >>= 1) {
      s += __shfl_down(s, off);
      s2 += __shfl_down(s2, off);
    }
    if (lane == 0) {
      float mean = s * (1.f / 256.f);
      float var = s2 * (1.f / 256.f) - mean * mean;
      gin[(size_t)mtok * 1056 + 1024 + br * 8 + w] = mean;
      gin[(size_t)mtok * 1056 + 1024 + br * 8 + 4 + w] = sqrtf(fmaxf(var, 1e-6f));
    }
  }
}

// ------- logits = mlph @ W2 + b2; temp-scaled softmax over 4 --------------
__global__ __launch_bounds__(256) void mlp2_gates(
    const float* __restrict__ mh, const float* __restrict__ W2,
    const float* __restrict__ b2, const float* __restrict__ glt,
    float* __restrict__ gates)
{
  int mtok = blockIdx.x, t = threadIdx.x;
  float p[16];
#pragma unroll
  for (int j = 0; j < 16; ++j) p[j] = 0.f;
  for (int k = t; k < 2048; k += 256) {
    float hv = mh[(size_t)mtok * 2048 + k];
    const float* wr = W2 + (size_t)k * 16;
#pragma unroll
    for (int j4 = 0; j4 < 4; ++j4) {
      float4 w4 = *(const float4*)(wr + j4 * 4);
      p[j4*4+0] = fmaf(hv, w4.x, p[j4*4+0]);
      p[j4*4+1] = fmaf(hv, w4.y, p[j4*4+1]);
      p[j4*4+2] = fmaf(hv, w4.z, p[j4*4+2]);
      p[j4*4+3] = fmaf(hv, w4.w, p[j4*4+3]);
    }
  }
#pragma unroll
  for (int j = 0; j < 16; ++j)
#pragma unroll
    for (int off = 32; off; off >>= 1) p[j] += __shfl_down(p[j], off);
  __shared__ float red[4][16];
  __shared__ float zl[16];
  int w = t >> 6;
  if ((t & 63) == 0) {
#pragma unroll
    for (int j = 0; j < 16; ++j) red[w][j] = p[j];
  }
  __syncthreads();
  if (t < 16) {
    float tot = red[0][t] + red[1][t] + red[2][t] + red[3][t] + b2[t];
    float tempv = log1pf(expf(glt[t >> 2])) + 1e-4f;
    zl[t] = tot / tempv;
  }
  __syncthreads();
  if (t < 4) {
    float z0 = zl[t*4], z1 = zl[t*4+1], z2 = zl[t*4+2], z3 = zl[t*4+3];
    float mx = fmaxf(fmaxf(z0, z1), fmaxf(z2, z3));
    float e0 = expf(z0 - mx), e1 = expf(z1 - mx), e2 = expf(z2 - mx), e3 = expf(z3 - mx);
    float inv = 1.f / (e0 + e1 + e2 + e3);
    gates[(size_t)mtok * 16 + t * 4 + 0] = e0 * inv;
    gates[(size_t)mtok * 16 + t * 4 + 1] = e1 * inv;
    gates[(size_t)mtok * 16 + t * 4 + 2] = e2 * inv;
    gates[(size_t)mtok * 16 + t * 4 + 3] = e3 * inv;
  }
}

// ------- o = gated mix, RMSNorm over head dim, * o_norm_w ------------------
__global__ __launch_bounds__(256) void combine_norm(
    const float* __restrict__ firs, const float* __restrict__ firl,
    const float* __restrict__ delta, const float* __restrict__ v,
    const float* __restrict__ gates, const float* __restrict__ onw,
    float* __restrict__ o)
{
  int mh = blockIdx.x;
  int mtok = mh >> 2, h = mh & 3;
  int t = threadIdx.x;
  int b = mtok >> 11, l = mtok & 2047;
  const float* g = gates + (size_t)mtok * 16 + h * 4;
  float w0 = g[0], w1 = g[1], w2 = g[2], w3 = g[3];
  size_t tb = (size_t)mtok * 1024 + h * 256 + t;
  float val = w0 * firs[tb] + w1 * firl[tb] + w2 * delta[tb]
            + w3 * v[(((size_t)(b * NH + h)) * Ls + l) * 256 + t];
  float s2 = val * val;
#pragma unroll
  for (int off = 32; off; off >>= 1) s2 += __shfl_down(s2, off);
  __shared__ float r4[4];
  if ((t & 63) == 0) r4[t >> 6] = s2;
  __syncthreads();
  float tot = r4[0] + r4[1] + r4[2] + r4[3];
  float rms = rsqrtf(tot * (1.f / 256.f) + 1e-5f);
  o[tb] = val * rms * onw[t];
}

// ---------------------------------------------------------------------------
extern "C" void kernel_launch(void* const* d_in, const int* in_sizes, int n_in,
                              void* d_out, int out_size, void* d_ws, size_t ws_size,
                              hipStream_t stream) {
  const float* x     = (const float*)d_in[0];
  const float* Wq    = (const float*)d_in[1];
  const float* Wk    = (const float*)d_in[2];
  const float* Wv    = (const float*)d_in[3];
  const float* Wb    = (const float*)d_in[4];
  const float* convq = (const float*)d_in[5];
  const float* convk = (const float*)d_in[6];
  const float* convv = (const float*)d_in[7];
  const float* firsw = (const float*)d_in[8];
  const float* firlw = (const float*)d_in[9];
  const float* mlpw1 = (const float*)d_in[10];
  const float* mlpb1 = (const float*)d_in[11];
  const float* mlpw2 = (const float*)d_in[12];
  const float* mlpb2 = (const float*)d_in[13];
  const float* glt   = (const float*)d_in[14];
  const float* onw   = (const float*)d_in[15];
  const float* Wo    = (const float*)d_in[16];
  float* ws = (float*)d_ws;

  fprintf(stderr, "[deltanet] ws_size=%zu need=%zu out_size=%d\n",
          ws_size, (size_t)WS_FLOATS * 4, out_size);

  dim3 blk(256);
  // projections (f32 GEMM) + beta
  gemm128<<<dim3(8, 32), blk, 0, stream>>>(x, Wq, ws + off_xq, 4096, 1024, 1024, nullptr, 0);
  gemm128<<<dim3(8, 32), blk, 0, stream>>>(x, Wk, ws + off_xk, 4096, 1024, 1024, nullptr, 0);
  gemm128<<<dim3(8, 32), blk, 0, stream>>>(x, Wv, ws + off_xv, 4096, 1024, 1024, nullptr, 0);
  beta_sigmoid<<<4096, blk, 0, stream>>>(x, Wb, ws + off_beta);
  // short causal convs + silu -> head-major q,k,v
  conv4_silu<<<16384, blk, 0, stream>>>(ws + off_xq, convq, ws + off_q);
  conv4_silu<<<16384, blk, 0, stream>>>(ws + off_xk, convk, ws + off_k);
  conv4_silu<<<16384, blk, 0, stream>>>(ws + off_xv, convv, ws + off_v);
  // l2norm + beta products (qn->xq, kn->xk, kb->q, vb->xv)
  prep_qkv<<<16384, blk, 0, stream>>>(ws + off_q, ws + off_k, ws + off_v, ws + off_beta,
                                      ws + off_xq, ws + off_xk, ws + off_q, ws + off_xv);
  // per-chunk T inverse, attn, w (->k slot), u (->xv slot, over vb)
  chunk_prep<<<512, blk, 0, stream>>>(ws + off_q, ws + off_xk, ws + off_xq, ws + off_xv,
                                      ws + off_attn, ws + off_k, ws + off_xv);
  // serial scan: u2 over u, o1 -> delta slot (q)
  delta_chain<<<256, blk, 0, stream>>>(ws + off_xk, ws + off_k, ws + off_xq,
                                       ws + off_xv, ws + off_q);
  // delta += attn @ u2
  delta_attn_add<<<512, blk, 0, stream>>>(ws + off_attn, ws + off_xv, ws + off_q);
  // FIR branches (token-major out)
  fir_conv<<<2048, blk, 0, stream>>>(ws + off_v, firlw, firsw, ws + off_firl, ws + off_firs);
  // gate input, MLP, gates
  build_gate_in<<<4096, blk, 0, stream>>>(x, ws + off_firs, ws + off_firl, ws + off_q,
                                          ws + off_v, ws + off_gin);
  gemm128<<<dim3(16, 32), blk, 0, stream>>>(ws + off_gin, mlpw1, ws + off_mlph,
                                            4096, 2048, 1056, mlpb1, 1);
  mlp2_gates<<<4096, blk, 0, stream>>>(ws + off_mlph, mlpw2, mlpb2, glt, ws + off_gates);
  // combine + RMSNorm (o -> xk slot), output projection
  combine_norm<<<16384, blk, 0, stream>>>(ws + off_firs, ws + off_firl, ws + off_q,
                                          ws + off_v, ws + off_gates, onw, ws + off_xk);
  gemm128<<<dim3(8, 32), blk, 0, stream>>>(ws + off_xk, Wo, (float*)d_out,
                                           4096, 1024, 1024, nullptr, 0);
}

// Round 2
// 1143.760 us; speedup vs baseline: 1.4618x; 1.4618x over previous
//
#include <hip/hip_runtime.h>
#include <hip/hip_bf16.h>

// ---------------------------------------------------------------------------
// DeltaNet forward, round 2:
//  - all large GEMMs moved to bf16 MFMA (16x16x32, 128x128 tile, BK=32,
//    global_load_lds 16B staging, B pre-transposed to [N][K] bf16)
//  - delta_chain: register prefetch of next chunk's w/q tiles (hide L2 lat)
//  - build_gate_in / combine_norm emit bf16 directly for the following GEMM
// Delta-rule recurrence itself stays f32 (precision headroom management).
// ---------------------------------------------------------------------------

#define DEVI __device__ __forceinline__
typedef unsigned int u32;
typedef unsigned short ushort_t;
typedef __attribute__((ext_vector_type(8))) short short8;
typedef __attribute__((ext_vector_type(4))) float floatx4;

constexpr int Ls = 2048, NH = 4;
constexpr int NCh = 64;

// workspace offsets (floats)
constexpr size_t off_xq   = 0;         // x@Wq -> qn -> (dead) [gin_bf unused here]
constexpr size_t off_xk   = 4194304;   // x@Wk -> kn -> (dead) -> w1_t (bf16)
constexpr size_t off_xv   = 8388608;   // x@Wv -> vb -> u -> u2 -> (dead) -> o_bf (bf16)
constexpr size_t off_q    = 12582912;  // q -> kb -> delta (o1)  [alive to combine]
constexpr size_t off_k    = 16777216;  // k -> w                 [dead after chain]
constexpr size_t off_v    = 20971520;  // v                      [alive to combine]
constexpr size_t off_beta = 25165824;  // beta -> (dead) -> Wo_t (bf16, uses beta+attn)
constexpr size_t off_attn = 25182208;  // attn [dead after delta_attn_add]
constexpr size_t off_firs = 25706496;  // x_bf (bf16, proj stage) -> firs f32
constexpr size_t off_firl = 29900800;  // Wq_t/Wk_t/Wv_t (bf16, proj stage) -> firl f32
constexpr size_t off_gin  = 34095104;  // gin_bf (bf16) [4096][1056]
constexpr size_t off_mlph = 38420480;  // mlph f32 [4096][2048]
constexpr size_t off_gates= 46809088;  // gates [4096][16]

DEVI float dot4(float4 a, float4 b) {
  return a.x*b.x + a.y*b.y + a.z*b.z + a.w*b.w;
}
DEVI float sigmoidf_(float x) { return 1.f / (1.f + expf(-x)); }
DEVI float siluf_(float x) { return x / (1.f + expf(-x)); }
DEVI float geluf_(float x) { return 0.5f * x * (1.f + erff(x * 0.7071067811865476f)); }
DEVI ushort_t f2bf(float f) {           // RNE f32 -> bf16 (finite inputs)
  union { float f; u32 u; } c{f};
  u32 r = (c.u + 0x7fffu + ((c.u >> 16) & 1u)) >> 16;
  return (ushort_t)r;
}
DEVI void async16(const void* g, void* l) {   // 16B global -> LDS (lane*16 auto)
  __builtin_amdgcn_global_load_lds(
      (const u32 __attribute__((address_space(1)))*)g,
      (u32 __attribute__((address_space(3)))*)l, 16, 0, 0);
}

// ---------------- f32 -> bf16, straight layout, 8 elem/thread --------------
__global__ __launch_bounds__(256) void to_bf16(
    const float* __restrict__ in, ushort_t* __restrict__ out, int n)
{
  int i = (blockIdx.x * 256 + threadIdx.x) * 8;
  if (i >= n) return;
  float4 a = *(const float4*)(in + i);
  float4 b = *(const float4*)(in + i + 4);
  ushort_t o[8] = { f2bf(a.x), f2bf(a.y), f2bf(a.z), f2bf(a.w),
                    f2bf(b.x), f2bf(b.y), f2bf(b.z), f2bf(b.w) };
  *(uint4*)(out + i) = *(uint4*)o;
}

// ---------------- f32 [K][N] -> bf16 [N][K] (transpose-convert) ------------
__global__ __launch_bounds__(256) void convT(
    const float* __restrict__ W, ushort_t* __restrict__ out, int Kq, int Nq)
{
  __shared__ ushort_t tile[32][33];
  int n0 = blockIdx.x * 32, k0 = blockIdx.y * 32;
  int tx = threadIdx.x & 31, ty = threadIdx.x >> 5;   // 32 x 8
#pragma unroll
  for (int r = 0; r < 32; r += 8)
    tile[ty + r][tx] = f2bf(W[(size_t)(k0 + ty + r) * Nq + n0 + tx]);
  __syncthreads();
#pragma unroll
  for (int r = 0; r < 32; r += 8)
    out[(size_t)(n0 + ty + r) * Kq + k0 + tx] = tile[tx][ty + r];
}

// ---------------- bf16 MFMA GEMM: C[M,N] f32 = A[M,K] @ Bt[N,K]^T ----------
// 128x128 tile, BK=32, 256 threads (4 waves 2x2), 16x16x32 bf16 MFMA.
__global__ __launch_bounds__(256) void gemm_bf16(
    const ushort_t* __restrict__ A, const ushort_t* __restrict__ Bt,
    float* __restrict__ C, int Nq, int Kq,
    const float* __restrict__ bias, int act)
{
  __shared__ ushort_t As[128 * 32];
  __shared__ ushort_t Bs[128 * 32];
  int t = threadIdx.x;
  int w = t >> 6, lane = t & 63;
  int m0 = blockIdx.y * 128, n0 = blockIdx.x * 128;
  floatx4 acc[4][4];
#pragma unroll
  for (int i = 0; i < 4; ++i)
#pragma unroll
    for (int j = 0; j < 4; ++j)
#pragma unroll
      for (int r = 0; r < 4; ++r) acc[i][j][r] = 0.f;

  int lrow = lane >> 2, lk8 = (lane & 3) * 8;
  for (int kt = 0; kt < Kq; kt += 32) {
#pragma unroll
    for (int r = 0; r < 2; ++r) {
      int seg = w * 2 + r;
      int row = seg * 16 + lrow;
      async16(A  + (size_t)(m0 + row) * Kq + kt + lk8, &As[seg * 512]);
      async16(Bt + (size_t)(n0 + row) * Kq + kt + lk8, &Bs[seg * 512]);
    }
    __syncthreads();      // compiler drains vmcnt before barrier
    short8 af[4], bf[4];
#pragma unroll
    for (int i = 0; i < 4; ++i) {
      int row = (w >> 1) * 64 + i * 16 + (lane & 15);
      af[i] = *(const short8*)&As[row * 32 + (lane >> 4) * 8];
    }
#pragma unroll
    for (int j = 0; j < 4; ++j) {
      int col = (w & 1) * 64 + j * 16 + (lane & 15);
      bf[j] = *(const short8*)&Bs[col * 32 + (lane >> 4) * 8];
    }
#pragma unroll
    for (int i = 0; i < 4; ++i)
#pragma unroll
      for (int j = 0; j < 4; ++j)
        acc[i][j] = __builtin_amdgcn_mfma_f32_16x16x32_bf16(af[i], bf[j], acc[i][j], 0, 0, 0);
    __syncthreads();
  }
#pragma unroll
  for (int i = 0; i < 4; ++i) {
    int rbase = m0 + (w >> 1) * 64 + i * 16 + ((lane >> 4) << 2);
#pragma unroll
    for (int j = 0; j < 4; ++j) {
      int col = n0 + (w & 1) * 64 + j * 16 + (lane & 15);
      float bv = act ? bias[col] : 0.f;
#pragma unroll
      for (int r = 0; r < 4; ++r) {
        float v = acc[i][j][r];
        if (act) v = geluf_(v + bv);
        C[(size_t)(rbase + r) * Nq + col] = v;
      }
    }
  }
}

// ---------------- beta = sigmoid(x @ Wb), head-major [bh][l] ---------------
__global__ __launch_bounds__(256) void beta_sigmoid(
    const float* __restrict__ x, const float* __restrict__ Wb,
    float* __restrict__ beta)
{
  int mtok = blockIdx.x, t = threadIdx.x;
  int b = mtok >> 11, l = mtok & 2047;
  float a0 = 0, a1 = 0, a2 = 0, a3 = 0;
  for (int k = t; k < 1024; k += 256) {
    float xv = x[(size_t)mtok * 1024 + k];
    float4 w4 = *(const float4*)(Wb + k * 4);
    a0 = fmaf(xv, w4.x, a0); a1 = fmaf(xv, w4.y, a1);
    a2 = fmaf(xv, w4.z, a2); a3 = fmaf(xv, w4.w, a3);
  }
#pragma unroll
  for (int off = 32; off; off >>= 1) {
    a0 += __shfl_down(a0, off); a1 += __shfl_down(a1, off);
    a2 += __shfl_down(a2, off); a3 += __shfl_down(a3, off);
  }
  __shared__ float red[4][4];
  int w = t >> 6;
  if ((t & 63) == 0) { red[w][0] = a0; red[w][1] = a1; red[w][2] = a2; red[w][3] = a3; }
  __syncthreads();
  if (t < 4) {
    float s = red[0][t] + red[1][t] + red[2][t] + red[3][t];
    beta[((size_t)(b * NH + t)) * Ls + l] = sigmoidf_(s);
  }
}

// ------- causal depthwise conv k=4 + silu; [b,l,c] -> head-major -----------
__global__ __launch_bounds__(256) void conv4_silu(
    const float* __restrict__ xin, const float* __restrict__ wt,
    float* __restrict__ out)
{
  int gid = blockIdx.x * 256 + threadIdx.x;
  int c = gid & 1023;
  int l = (gid >> 10) & 2047;
  int b = gid >> 21;
  float4 w4 = *(const float4*)(wt + c * 4);
  float wj[4] = {w4.x, w4.y, w4.z, w4.w};
  const float* xp = xin + ((size_t)b * Ls) * 1024 + c;
  float acc = 0.f;
#pragma unroll
  for (int j = 0; j < 4; ++j) {
    int ls = l - 3 + j;
    float xv = (ls >= 0) ? xp[(size_t)ls * 1024] : 0.f;
    acc = fmaf(wj[j], xv, acc);
  }
  float y = siluf_(acc);
  int h = c >> 8, d = c & 255;
  out[(((size_t)(b * NH + h)) * Ls + l) * 256 + d] = y;
}

// ------- l2norm q,k; kb = kn*beta; vb = v*beta -----------------------------
__global__ __launch_bounds__(256) void prep_qkv(
    const float* __restrict__ q, const float* __restrict__ k,
    const float* __restrict__ v, const float* __restrict__ beta,
    float* __restrict__ qn, float* __restrict__ kn,
    float* __restrict__ kb, float* __restrict__ vb)
{
  int i = blockIdx.x;
  int t = threadIdx.x;
  size_t base = (size_t)i * 256 + t;
  float qv = q[base], kv = k[base], vv = v[base];
  float sq = qv * qv, sk = kv * kv;
#pragma unroll
  for (int off = 32; off; off >>= 1) {
    sq += __shfl_down(sq, off);
    sk += __shfl_down(sk, off);
  }
  __shared__ float rq_[4], rk_[4];
  int w = t >> 6;
  if ((t & 63) == 0) { rq_[w] = sq; rk_[w] = sk; }
  __syncthreads();
  sq = rq_[0] + rq_[1] + rq_[2] + rq_[3];
  sk = rk_[0] + rk_[1] + rk_[2] + rk_[3];
  float rq = rsqrtf(sq + 1e-6f), rk = rsqrtf(sk + 1e-6f);
  float bt = beta[i];
  qn[base] = qv * rq;
  kn[base] = kv * rk;
  kb[base] = kv * rk * bt;
  vb[base] = vv * bt;
}

// ------- per (b,h,chunk): A, T=inv(I+A), attn, w=T@kb, u=T@vb --------------
__global__ __launch_bounds__(256) void chunk_prep(
    const float* __restrict__ kb, const float* __restrict__ kn,
    const float* __restrict__ qn, const float* __restrict__ vb,
    float* __restrict__ attn_g, float* __restrict__ w_out,
    float* __restrict__ u_out)
{
  __shared__ float kbs[32][260], kns[32][260], bufs[32][260];
  __shared__ float Am[32][33], Tm[32][33];
  int t = threadIdx.x;
  int cc = blockIdx.x & 63, bh = blockIdx.x >> 6;
  size_t gbase = ((size_t)bh * Ls + cc * 32) * 256;
#pragma unroll
  for (int r = 0; r < 8; ++r) {
    int s = r * 256 + t; int row = s >> 6, c4 = (s & 63) * 4;
    *(float4*)&kbs[row][c4]  = *(const float4*)(kb + gbase + row * 256 + c4);
    *(float4*)&kns[row][c4]  = *(const float4*)(kn + gbase + row * 256 + c4);
    *(float4*)&bufs[row][c4] = *(const float4*)(qn + gbase + row * 256 + c4);
  }
  __syncthreads();
  float* ag = attn_g + ((size_t)bh * 64 + cc) * 1024;
#pragma unroll
  for (int p = 0; p < 4; ++p) {
    int pair = p * 256 + t, i = pair >> 5, j = pair & 31;
    float aA = 0.f, aQ = 0.f;
#pragma unroll 8
    for (int kk = 0; kk < 256; kk += 4) {
      float4 kf = *(float4*)&kns[j][kk];
      float4 bfv = *(float4*)&kbs[i][kk];
      float4 qf = *(float4*)&bufs[i][kk];
      aA += dot4(bfv, kf);
      aQ += dot4(qf, kf);
    }
    Am[i][j] = (j < i) ? aA : 0.f;
    ag[i * 32 + j] = (j <= i) ? aQ : 0.f;
  }
  __syncthreads();
  if (t < 32) {
    for (int i2 = 0; i2 < 32; ++i2) Tm[i2][t] = (i2 == t) ? 1.f : 0.f;
  }
  __syncthreads();
  for (int i2 = 1; i2 < 32; ++i2) {
    if (t < i2) {
      float s = 0.f;
      for (int m2 = t; m2 < i2; ++m2) s = fmaf(Am[i2][m2], Tm[m2][t], s);
      Tm[i2][t] = -s;
    }
    __syncthreads();
  }
#pragma unroll
  for (int r = 0; r < 8; ++r) {
    int s = r * 256 + t; int row = s >> 6, c4 = (s & 63) * 4;
    *(float4*)&bufs[row][c4] = *(const float4*)(vb + gbase + row * 256 + c4);
  }
  __syncthreads();
  int d4 = (t & 63) * 4, i8 = (t >> 6) * 8;
#pragma unroll
  for (int r = 0; r < 8; ++r) {
    int i = i8 + r;
    float4 wa = make_float4(0,0,0,0), ua = make_float4(0,0,0,0);
#pragma unroll
    for (int m2 = 0; m2 < 32; ++m2) {
      float tv = Tm[i][m2];
      float4 kbf = *(float4*)&kbs[m2][d4];
      float4 vbf = *(float4*)&bufs[m2][d4];
      wa.x = fmaf(tv, kbf.x, wa.x); wa.y = fmaf(tv, kbf.y, wa.y);
      wa.z = fmaf(tv, kbf.z, wa.z); wa.w = fmaf(tv, kbf.w, wa.w);
      ua.x = fmaf(tv, vbf.x, ua.x); ua.y = fmaf(tv, vbf.y, ua.y);
      ua.z = fmaf(tv, vbf.z, ua.z); ua.w = fmaf(tv, vbf.w, ua.w);
    }
    *(float4*)(w_out + gbase + i * 256 + d4) = wa;
    *(float4*)(u_out + gbase + i * 256 + d4) = ua;
  }
}

// ------- serial chunk scan with register prefetch of next chunk ------------
__global__ __launch_bounds__(256) void delta_chain(
    const float* __restrict__ kn, const float* __restrict__ w_g,
    const float* __restrict__ qn, float* __restrict__ u_g,
    float* __restrict__ o1_g)
{
  __shared__ float wis[32][264], qis[32][264];
  __shared__ float St[8][264];
  __shared__ float u2s[32][8];
  int t = threadIdx.x;
  int js = blockIdx.x & 31, bh = blockIdx.x >> 5;
  int j0 = js * 8;
  int b = bh >> 2, h = bh & 3;
  const float* knp = kn + (size_t)bh * Ls * 256;
  const float* wp  = w_g + (size_t)bh * Ls * 256;
  const float* qp  = qn + (size_t)bh * Ls * 256;
  float* up = u_g + (size_t)bh * Ls * 256;
  float Sreg[8];
#pragma unroll
  for (int jj = 0; jj < 8; ++jj) { Sreg[jj] = 0.f; St[jj][t] = 0.f; }
  int ui = t >> 3, uj = t & 7;
  int srow = t >> 6, scol = (t & 63) * 4;
  float4 wpre[8], qpre[8];
#pragma unroll
  for (int r = 0; r < 8; ++r) {
    int row = r * 4 + srow;
    wpre[r] = *(const float4*)(wp + (size_t)row * 256 + scol);
    qpre[r] = *(const float4*)(qp + (size_t)row * 256 + scol);
  }
  __syncthreads();
  for (int cc = 0; cc < NCh; ++cc) {
    size_t cb = (size_t)cc * 8192;
#pragma unroll
    for (int r = 0; r < 8; ++r) {
      int row = r * 4 + srow;
      *(float4*)&wis[row][scol] = wpre[r];
      *(float4*)&qis[row][scol] = qpre[r];
    }
    __syncthreads();
    if (cc + 1 < NCh) {            // prefetch next chunk; consumed next iter
      size_t nb = cb + 8192;
#pragma unroll
      for (int r = 0; r < 8; ++r) {
        int row = r * 4 + srow;
        wpre[r] = *(const float4*)(wp + nb + (size_t)row * 256 + scol);
        qpre[r] = *(const float4*)(qp + nb + (size_t)row * 256 + scol);
      }
    }
    float kcol[32];
#pragma unroll
    for (int i = 0; i < 32; ++i) kcol[i] = knp[cb + i * 256 + t];
    float uval = up[cb + ui * 256 + j0 + uj];
    float du = 0.f, accO = 0.f;
#pragma unroll 8
    for (int kk = 0; kk < 256; kk += 4) {
      float4 s4 = *(float4*)&St[uj][kk];
      float4 w4 = *(float4*)&wis[ui][kk];
      float4 q4 = *(float4*)&qis[ui][kk];
      du   += dot4(w4, s4);
      accO += dot4(q4, s4);
    }
    float accU = uval - du;
    u2s[ui][uj] = accU;
    up[cb + ui * 256 + j0 + uj] = accU;
    int l = cc * 32 + ui;
    o1_g[(((size_t)b * Ls + l) * NH + h) * 256 + j0 + uj] = accO;
    __syncthreads();
#pragma unroll
    for (int i = 0; i < 32; ++i) {
      float f = kcol[i];
      float4 u20 = *(float4*)&u2s[i][0];
      float4 u21 = *(float4*)&u2s[i][4];
      Sreg[0] = fmaf(f, u20.x, Sreg[0]); Sreg[1] = fmaf(f, u20.y, Sreg[1]);
      Sreg[2] = fmaf(f, u20.z, Sreg[2]); Sreg[3] = fmaf(f, u20.w, Sreg[3]);
      Sreg[4] = fmaf(f, u21.x, Sreg[4]); Sreg[5] = fmaf(f, u21.y, Sreg[5]);
      Sreg[6] = fmaf(f, u21.z, Sreg[6]); Sreg[7] = fmaf(f, u21.w, Sreg[7]);
    }
#pragma unroll
    for (int jj = 0; jj < 8; ++jj) St[jj][t] = Sreg[jj];
    __syncthreads();
  }
}

// ------- delta += attn @ u2, parallel over (bh, chunk) ---------------------
__global__ __launch_bounds__(256) void delta_attn_add(
    const float* __restrict__ attn_g, const float* __restrict__ u2_g,
    float* __restrict__ delta)
{
  __shared__ float u2s[32][260];
  __shared__ float at[32][36];
  int t = threadIdx.x;
  int cc = blockIdx.x & 63, bh = blockIdx.x >> 6;
  int b = bh >> 2, h = bh & 3;
  size_t gbase = ((size_t)bh * Ls + cc * 32) * 256;
#pragma unroll
  for (int r = 0; r < 8; ++r) {
    int s = r * 256 + t; int row = s >> 6, c4 = (s & 63) * 4;
    *(float4*)&u2s[row][c4] = *(const float4*)(u2_g + gbase + row * 256 + c4);
  }
  *(float4*)&at[t >> 3][(t & 7) * 4] =
      *(const float4*)(attn_g + ((size_t)bh * 64 + cc) * 1024 + t * 4);
  __syncthreads();
  int d4 = (t & 63) * 4, i8 = (t >> 6) * 8;
#pragma unroll
  for (int r = 0; r < 8; ++r) {
    int i = i8 + r;
    int l = cc * 32 + i;
    size_t ob = (((size_t)b * Ls + l) * NH + h) * 256 + d4;
    float4 acc = *(float4*)(delta + ob);
#pragma unroll
    for (int m = 0; m < 32; ++m) {
      float av = at[i][m];
      float4 uf = *(float4*)&u2s[m][d4];
      acc.x = fmaf(av, uf.x, acc.x); acc.y = fmaf(av, uf.y, acc.y);
      acc.z = fmaf(av, uf.z, acc.z); acc.w = fmaf(av, uf.w, acc.w);
    }
    *(float4*)(delta + ob) = acc;
  }
}

// ------- FIR 63-tap + 3-tap causal depthwise over v ------------------------
__global__ __launch_bounds__(256) void fir_conv(
    const float* __restrict__ v, const float* __restrict__ wlg,
    const float* __restrict__ wsg, float* __restrict__ firl,
    float* __restrict__ firs)
{
  __shared__ float vt[256][71];
  int t = threadIdx.x;
  int lt = blockIdx.x & 255;
  int bh = blockIdx.x >> 8;
  int b = bh >> 2, h = bh & 3;
  int l0 = lt * 8;
  const float* vp = v + (size_t)bh * Ls * 256;
  for (int r = 0; r < 70; ++r) {
    int ls = l0 - 62 + r;
    vt[t][r] = (ls >= 0) ? vp[(size_t)ls * 256 + t] : 0.f;
  }
  float TL[63], TS3[3];
#pragma unroll
  for (int j = 0; j < 63; ++j) TL[j] = wlg[((size_t)h * 256 + t) * 63 + j];
#pragma unroll
  for (int j = 0; j < 3; ++j) TS3[j] = wsg[((size_t)h * 256 + t) * 3 + j];
  __syncthreads();
  float aL[8] = {0,0,0,0,0,0,0,0}, aS[8] = {0,0,0,0,0,0,0,0};
#pragma unroll
  for (int r = 0; r < 70; ++r) {
    float vm = vt[t][r];
#pragma unroll
    for (int p = 0; p < 8; ++p) {
      int jl = r - p;
      if (jl >= 0 && jl < 63) aL[p] = fmaf(vm, TL[jl], aL[p]);
      int jssrc = r - 60 - p;
      if (jssrc >= 0 && jssrc < 3) aS[p] = fmaf(vm, TS3[jssrc], aS[p]);
    }
  }
#pragma unroll
  for (int p = 0; p < 8; ++p) {
    int l = l0 + p;
    size_t ob = (((size_t)b * Ls + l) * NH + h) * 256 + t;
    firl[ob] = aL[p];
    firs[ob] = aS[p];
  }
}

// ------- gate_in (bf16) = [x | stats(firs) | stats(firl) | stats(delta) | stats(v)]
__global__ __launch_bounds__(256) void build_gate_in_bf(
    const float* __restrict__ x, const float* __restrict__ firs,
    const float* __restrict__ firl, const float* __restrict__ delta,
    const float* __restrict__ v, ushort_t* __restrict__ gin)
{
  int mtok = blockIdx.x, t = threadIdx.x;
  int b = mtok >> 11, l = mtok & 2047;
  float4 xv = *(const float4*)(x + (size_t)mtok * 1024 + t * 4);
  ushort4 xo = make_ushort4(f2bf(xv.x), f2bf(xv.y), f2bf(xv.z), f2bf(xv.w));
  *(ushort4*)(gin + (size_t)mtok * 1056 + t * 4) = xo;
  int w = t >> 6, lane = t & 63;
  for (int br = 0; br < 4; ++br) {
    float s = 0.f, s2 = 0.f;
#pragma unroll
    for (int r = 0; r < 4; ++r) {
      int d = lane + r * 64;
      float val;
      if (br == 0)      val = firs [(size_t)mtok * 1024 + w * 256 + d];
      else if (br == 1) val = firl [(size_t)mtok * 1024 + w * 256 + d];
      else if (br == 2) val = delta[(size_t)mtok * 1024 + w * 256 + d];
      else              val = v[(((size_t)(b * NH + w)) * Ls + l) * 256 + d];
      s += val; s2 = fmaf(val, val, s2);
    }
#pragma unroll
    for (int off = 32; off; off >>= 1) {
      s += __shfl_down(s, off);
      s2 += __shfl_down(s2, off);
    }
    if (lane == 0) {
      float mean = s * (1.f / 256.f);
      float var = s2 * (1.f / 256.f) - mean * mean;
      gin[(size_t)mtok * 1056 + 1024 + br * 8 + w] = f2bf(mean);
      gin[(size_t)mtok * 1056 + 1024 + br * 8 + 4 + w] = f2bf(sqrtf(fmaxf(var, 1e-6f)));
    }
  }
}

// ------- logits = mlph @ W2 + b2; temp-scaled softmax over 4 ---------------
__global__ __launch_bounds__(256) void mlp2_gates(
    const float* __restrict__ mh, const float* __restrict__ W2,
    const float* __restrict__ b2, const float* __restrict__ glt,
    float* __restrict__ gates)
{
  int mtok = blockIdx.x, t = threadIdx.x;
  float p[16];
#pragma unroll
  for (int j = 0; j < 16; ++j) p[j] = 0.f;
  for (int k = t; k < 2048; k += 256) {
    float hv = mh[(size_t)mtok * 2048 + k];
    const float* wr = W2 + (size_t)k * 16;
#pragma unroll
    for (int j4 = 0; j4 < 4; ++j4) {
      float4 w4 = *(const float4*)(wr + j4 * 4);
      p[j4*4+0] = fmaf(hv, w4.x, p[j4*4+0]);
      p[j4*4+1] = fmaf(hv, w4.y, p[j4*4+1]);
      p[j4*4+2] = fmaf(hv, w4.z, p[j4*4+2]);
      p[j4*4+3] = fmaf(hv, w4.w, p[j4*4+3]);
    }
  }
#pragma unroll
  for (int j = 0; j < 16; ++j)
#pragma unroll
    for (int off = 32; off; off >>= 1) p[j] += __shfl_down(p[j], off);
  __shared__ float red[4][16];
  __shared__ float zl[16];
  int w = t >> 6;
  if ((t & 63) == 0) {
#pragma unroll
    for (int j = 0; j < 16; ++j) red[w][j] = p[j];
  }
  __syncthreads();
  if (t < 16) {
    float tot = red[0][t] + red[1][t] + red[2][t] + red[3][t] + b2[t];
    float tempv = log1pf(expf(glt[t >> 2])) + 1e-4f;
    zl[t] = tot / tempv;
  }
  __syncthreads();
  if (t < 4) {
    float z0 = zl[t*4], z1 = zl[t*4+1], z2 = zl[t*4+2], z3 = zl[t*4+3];
    float mx = fmaxf(fmaxf(z0, z1), fmaxf(z2, z3));
    float e0 = expf(z0 - mx), e1 = expf(z1 - mx), e2 = expf(z2 - mx), e3 = expf(z3 - mx);
    float inv = 1.f / (e0 + e1 + e2 + e3);
    gates[(size_t)mtok * 16 + t * 4 + 0] = e0 * inv;
    gates[(size_t)mtok * 16 + t * 4 + 1] = e1 * inv;
    gates[(size_t)mtok * 16 + t * 4 + 2] = e2 * inv;
    gates[(size_t)mtok * 16 + t * 4 + 3] = e3 * inv;
  }
}

// ------- o = gated mix, RMSNorm, * o_norm_w -> bf16 ------------------------
__global__ __launch_bounds__(256) void combine_norm_bf(
    const float* __restrict__ firs, const float* __restrict__ firl,
    const float* __restrict__ delta, const float* __restrict__ v,
    const float* __restrict__ gates, const float* __restrict__ onw,
    ushort_t* __restrict__ o)
{
  int mh = blockIdx.x;
  int mtok = mh >> 2, h = mh & 3;
  int t = threadIdx.x;
  int b = mtok >> 11, l = mtok & 2047;
  const float* g = gates + (size_t)mtok * 16 + h * 4;
  float w0 = g[0], w1 = g[1], w2 = g[2], w3 = g[3];
  size_t tb = (size_t)mtok * 1024 + h * 256 + t;
  float val = w0 * firs[tb] + w1 * firl[tb] + w2 * delta[tb]
            + w3 * v[(((size_t)(b * NH + h)) * Ls + l) * 256 + t];
  float s2 = val * val;
#pragma unroll
  for (int off = 32; off; off >>= 1) s2 += __shfl_down(s2, off);
  __shared__ float r4[4];
  if ((t & 63) == 0) r4[t >> 6] = s2;
  __syncthreads();
  float tot = r4[0] + r4[1] + r4[2] + r4[3];
  float rms = rsqrtf(tot * (1.f / 256.f) + 1e-5f);
  o[tb] = f2bf(val * rms * onw[t]);
}

// ---------------------------------------------------------------------------
extern "C" void kernel_launch(void* const* d_in, const int* in_sizes, int n_in,
                              void* d_out, int out_size, void* d_ws, size_t ws_size,
                              hipStream_t stream) {
  const float* x     = (const float*)d_in[0];
  const float* Wq    = (const float*)d_in[1];
  const float* Wk    = (const float*)d_in[2];
  const float* Wv    = (const float*)d_in[3];
  const float* Wb    = (const float*)d_in[4];
  const float* convq = (const float*)d_in[5];
  const float* convk = (const float*)d_in[6];
  const float* convv = (const float*)d_in[7];
  const float* firsw = (const float*)d_in[8];
  const float* firlw = (const float*)d_in[9];
  const float* mlpw1 = (const float*)d_in[10];
  const float* mlpb1 = (const float*)d_in[11];
  const float* mlpw2 = (const float*)d_in[12];
  const float* mlpb2 = (const float*)d_in[13];
  const float* glt   = (const float*)d_in[14];
  const float* onw   = (const float*)d_in[15];
  const float* Wo    = (const float*)d_in[16];
  float* ws = (float*)d_ws;

  ushort_t* x_bf  = (ushort_t*)(ws + off_firs);
  ushort_t* Wq_t  = (ushort_t*)(ws + off_firl);
  ushort_t* Wk_t  = (ushort_t*)(ws + off_firl + 524288);
  ushort_t* Wv_t  = (ushort_t*)(ws + off_firl + 1048576);
  ushort_t* gin_bf= (ushort_t*)(ws + off_gin);
  ushort_t* w1_t  = (ushort_t*)(ws + off_xk);
  ushort_t* o_bf  = (ushort_t*)(ws + off_xv);
  ushort_t* Wo_t  = (ushort_t*)(ws + off_beta);

  dim3 blk(256);
  // stage 1: bf16 conversion + MFMA projections
  to_bf16<<<2048, blk, 0, stream>>>(x, x_bf, 4194304);
  convT<<<dim3(32, 32), blk, 0, stream>>>(Wq, Wq_t, 1024, 1024);
  convT<<<dim3(32, 32), blk, 0, stream>>>(Wk, Wk_t, 1024, 1024);
  convT<<<dim3(32, 32), blk, 0, stream>>>(Wv, Wv_t, 1024, 1024);
  gemm_bf16<<<dim3(8, 32), blk, 0, stream>>>(x_bf, Wq_t, ws + off_xq, 1024, 1024, nullptr, 0);
  gemm_bf16<<<dim3(8, 32), blk, 0, stream>>>(x_bf, Wk_t, ws + off_xk, 1024, 1024, nullptr, 0);
  gemm_bf16<<<dim3(8, 32), blk, 0, stream>>>(x_bf, Wv_t, ws + off_xv, 1024, 1024, nullptr, 0);
  beta_sigmoid<<<4096, blk, 0, stream>>>(x, Wb, ws + off_beta);
  // short causal convs + silu -> head-major q,k,v
  conv4_silu<<<16384, blk, 0, stream>>>(ws + off_xq, convq, ws + off_q);
  conv4_silu<<<16384, blk, 0, stream>>>(ws + off_xk, convk, ws + off_k);
  conv4_silu<<<16384, blk, 0, stream>>>(ws + off_xv, convv, ws + off_v);
  // l2norm + beta products
  prep_qkv<<<16384, blk, 0, stream>>>(ws + off_q, ws + off_k, ws + off_v, ws + off_beta,
                                      ws + off_xq, ws + off_xk, ws + off_q, ws + off_xv);
  chunk_prep<<<512, blk, 0, stream>>>(ws + off_q, ws + off_xk, ws + off_xq, ws + off_xv,
                                      ws + off_attn, ws + off_k, ws + off_xv);
  delta_chain<<<256, blk, 0, stream>>>(ws + off_xk, ws + off_k, ws + off_xq,
                                       ws + off_xv, ws + off_q);
  delta_attn_add<<<512, blk, 0, stream>>>(ws + off_attn, ws + off_xv, ws + off_q);
  // FIR branches (overwrites x_bf / W*_t regions — dead by now)
  fir_conv<<<2048, blk, 0, stream>>>(ws + off_v, firlw, firsw, ws + off_firl, ws + off_firs);
  // gate input (bf16), MLP1 (MFMA, gelu), gates
  build_gate_in_bf<<<4096, blk, 0, stream>>>(x, ws + off_firs, ws + off_firl, ws + off_q,
                                             ws + off_v, gin_bf);
  convT<<<dim3(64, 33), blk, 0, stream>>>(mlpw1, w1_t, 1056, 2048);
  gemm_bf16<<<dim3(16, 32), blk, 0, stream>>>(gin_bf, w1_t, ws + off_mlph, 2048, 1056, mlpb1, 1);
  mlp2_gates<<<4096, blk, 0, stream>>>(ws + off_mlph, mlpw2, mlpb2, glt, ws + off_gates);
  // combine + RMSNorm -> bf16, output projection (MFMA)
  combine_norm_bf<<<16384, blk, 0, stream>>>(ws + off_firs, ws + off_firl, ws + off_q,
                                             ws + off_v, ws + off_gates, onw, o_bf);
  convT<<<dim3(32, 32), blk, 0, stream>>>(Wo, Wo_t, 1024, 1024);
  gemm_bf16<<<dim3(8, 32), blk, 0, stream>>>(o_bf, Wo_t, (float*)d_out, 1024, 1024, nullptr, 0);
}

// Round 3
// 808.520 us; speedup vs baseline: 2.0679x; 1.4146x over previous
//
#include <hip/hip_runtime.h>
#include <hip/hip_bf16.h>

// ---------------------------------------------------------------------------
// DeltaNet forward, round 3:
//  - delta_chain rewritten on MFMA: S held in f32 accumulators (never
//    rounded), per-chunk split-bf16 (hi+lo) LDS copy as B-operand, u2 split
//    likewise; w/q/knT pre-converted to bf16 by chunk_prep (w negated so
//    u2 = u + (-w)@S accumulates directly).
//  - round-2 register-prefetch delta_chain (spill disaster) removed.
//  - everything else identical to round 2 (passed at absmax 0.0156).
// ---------------------------------------------------------------------------

#define DEVI __device__ __forceinline__
typedef unsigned int u32;
typedef unsigned short ushort_t;
typedef __attribute__((ext_vector_type(8))) short short8;
typedef __attribute__((ext_vector_type(4))) float floatx4;

constexpr int Ls = 2048, NH = 4;
constexpr int NCh = 64;

// workspace offsets (floats)
constexpr size_t off_xq   = 0;         // x@Wq -> qn
constexpr size_t off_xk   = 4194304;   // x@Wk -> kn -> (dead) -> w1_t (bf16)
constexpr size_t off_xv   = 8388608;   // x@Wv -> vb -> u -> u2 -> (dead) -> o_bf
constexpr size_t off_q    = 12582912;  // q -> kb -> delta (o1)
constexpr size_t off_k    = 16777216;  // k (f32 w slot now unused after prep_qkv)
constexpr size_t off_v    = 20971520;  // v (alive to the end)
constexpr size_t off_beta = 25165824;  // beta -> Wo_t (bf16)
constexpr size_t off_attn = 25182208;  // attn
constexpr size_t off_firs = 25706496;  // x_bf -> {wn_bf, q_bf} (bf16) -> firs f32
constexpr size_t off_firl = 29900800;  // W*_t -> knT_bf (bf16) -> firl f32
constexpr size_t off_gin  = 34095104;  // gin_bf (bf16)
constexpr size_t off_mlph = 38420480;  // mlph f32
constexpr size_t off_gates= 46809088;  // gates

DEVI float dot4(float4 a, float4 b) {
  return a.x*b.x + a.y*b.y + a.z*b.z + a.w*b.w;
}
DEVI float sigmoidf_(float x) { return 1.f / (1.f + expf(-x)); }
DEVI float siluf_(float x) { return x / (1.f + expf(-x)); }
DEVI float geluf_(float x) { return 0.5f * x * (1.f + erff(x * 0.7071067811865476f)); }
DEVI ushort_t f2bf(float f) {
  union { float f; u32 u; } c{f};
  u32 r = (c.u + 0x7fffu + ((c.u >> 16) & 1u)) >> 16;
  return (ushort_t)r;
}
DEVI float bf2f(ushort_t h) {
  union { u32 u; float f; } c; c.u = ((u32)h) << 16; return c.f;
}
DEVI void async16(const void* g, void* l) {
  __builtin_amdgcn_global_load_lds(
      (const u32 __attribute__((address_space(1)))*)g,
      (u32 __attribute__((address_space(3)))*)l, 16, 0, 0);
}

// ---------------- f32 -> bf16 ----------------------------------------------
__global__ __launch_bounds__(256) void to_bf16(
    const float* __restrict__ in, ushort_t* __restrict__ out, int n)
{
  int i = (blockIdx.x * 256 + threadIdx.x) * 8;
  if (i >= n) return;
  float4 a = *(const float4*)(in + i);
  float4 b = *(const float4*)(in + i + 4);
  ushort_t o[8] = { f2bf(a.x), f2bf(a.y), f2bf(a.z), f2bf(a.w),
                    f2bf(b.x), f2bf(b.y), f2bf(b.z), f2bf(b.w) };
  *(uint4*)(out + i) = *(uint4*)o;
}

// ---------------- f32 [K][N] -> bf16 [N][K] --------------------------------
__global__ __launch_bounds__(256) void convT(
    const float* __restrict__ W, ushort_t* __restrict__ out, int Kq, int Nq)
{
  __shared__ ushort_t tile[32][33];
  int n0 = blockIdx.x * 32, k0 = blockIdx.y * 32;
  int tx = threadIdx.x & 31, ty = threadIdx.x >> 5;
#pragma unroll
  for (int r = 0; r < 32; r += 8)
    tile[ty + r][tx] = f2bf(W[(size_t)(k0 + ty + r) * Nq + n0 + tx]);
  __syncthreads();
#pragma unroll
  for (int r = 0; r < 32; r += 8)
    out[(size_t)(n0 + ty + r) * Kq + k0 + tx] = tile[tx][ty + r];
}

// ---------------- bf16 MFMA GEMM (unchanged from round 2) ------------------
__global__ __launch_bounds__(256) void gemm_bf16(
    const ushort_t* __restrict__ A, const ushort_t* __restrict__ Bt,
    float* __restrict__ C, int Nq, int Kq,
    const float* __restrict__ bias, int act)
{
  __shared__ ushort_t As[128 * 32];
  __shared__ ushort_t Bs[128 * 32];
  int t = threadIdx.x;
  int w = t >> 6, lane = t & 63;
  int m0 = blockIdx.y * 128, n0 = blockIdx.x * 128;
  floatx4 acc[4][4];
#pragma unroll
  for (int i = 0; i < 4; ++i)
#pragma unroll
    for (int j = 0; j < 4; ++j)
#pragma unroll
      for (int r = 0; r < 4; ++r) acc[i][j][r] = 0.f;

  int lrow = lane >> 2, lk8 = (lane & 3) * 8;
  for (int kt = 0; kt < Kq; kt += 32) {
#pragma unroll
    for (int r = 0; r < 2; ++r) {
      int seg = w * 2 + r;
      int row = seg * 16 + lrow;
      async16(A  + (size_t)(m0 + row) * Kq + kt + lk8, &As[seg * 512]);
      async16(Bt + (size_t)(n0 + row) * Kq + kt + lk8, &Bs[seg * 512]);
    }
    __syncthreads();
    short8 af[4], bf[4];
#pragma unroll
    for (int i = 0; i < 4; ++i) {
      int row = (w >> 1) * 64 + i * 16 + (lane & 15);
      af[i] = *(const short8*)&As[row * 32 + (lane >> 4) * 8];
    }
#pragma unroll
    for (int j = 0; j < 4; ++j) {
      int col = (w & 1) * 64 + j * 16 + (lane & 15);
      bf[j] = *(const short8*)&Bs[col * 32 + (lane >> 4) * 8];
    }
#pragma unroll
    for (int i = 0; i < 4; ++i)
#pragma unroll
      for (int j = 0; j < 4; ++j)
        acc[i][j] = __builtin_amdgcn_mfma_f32_16x16x32_bf16(af[i], bf[j], acc[i][j], 0, 0, 0);
    __syncthreads();
  }
#pragma unroll
  for (int i = 0; i < 4; ++i) {
    int rbase = m0 + (w >> 1) * 64 + i * 16 + ((lane >> 4) << 2);
#pragma unroll
    for (int j = 0; j < 4; ++j) {
      int col = n0 + (w & 1) * 64 + j * 16 + (lane & 15);
      float bv = act ? bias[col] : 0.f;
#pragma unroll
      for (int r = 0; r < 4; ++r) {
        float v = acc[i][j][r];
        if (act) v = geluf_(v + bv);
        C[(size_t)(rbase + r) * Nq + col] = v;
      }
    }
  }
}

// ---------------- beta = sigmoid(x @ Wb) -----------------------------------
__global__ __launch_bounds__(256) void beta_sigmoid(
    const float* __restrict__ x, const float* __restrict__ Wb,
    float* __restrict__ beta)
{
  int mtok = blockIdx.x, t = threadIdx.x;
  int b = mtok >> 11, l = mtok & 2047;
  float a0 = 0, a1 = 0, a2 = 0, a3 = 0;
  for (int k = t; k < 1024; k += 256) {
    float xv = x[(size_t)mtok * 1024 + k];
    float4 w4 = *(const float4*)(Wb + k * 4);
    a0 = fmaf(xv, w4.x, a0); a1 = fmaf(xv, w4.y, a1);
    a2 = fmaf(xv, w4.z, a2); a3 = fmaf(xv, w4.w, a3);
  }
#pragma unroll
  for (int off = 32; off; off >>= 1) {
    a0 += __shfl_down(a0, off); a1 += __shfl_down(a1, off);
    a2 += __shfl_down(a2, off); a3 += __shfl_down(a3, off);
  }
  __shared__ float red[4][4];
  int w = t >> 6;
  if ((t & 63) == 0) { red[w][0] = a0; red[w][1] = a1; red[w][2] = a2; red[w][3] = a3; }
  __syncthreads();
  if (t < 4) {
    float s = red[0][t] + red[1][t] + red[2][t] + red[3][t];
    beta[((size_t)(b * NH + t)) * Ls + l] = sigmoidf_(s);
  }
}

// ------- causal depthwise conv k=4 + silu ----------------------------------
__global__ __launch_bounds__(256) void conv4_silu(
    const float* __restrict__ xin, const float* __restrict__ wt,
    float* __restrict__ out)
{
  int gid = blockIdx.x * 256 + threadIdx.x;
  int c = gid & 1023;
  int l = (gid >> 10) & 2047;
  int b = gid >> 21;
  float4 w4 = *(const float4*)(wt + c * 4);
  float wj[4] = {w4.x, w4.y, w4.z, w4.w};
  const float* xp = xin + ((size_t)b * Ls) * 1024 + c;
  float acc = 0.f;
#pragma unroll
  for (int j = 0; j < 4; ++j) {
    int ls = l - 3 + j;
    float xv = (ls >= 0) ? xp[(size_t)ls * 1024] : 0.f;
    acc = fmaf(wj[j], xv, acc);
  }
  float y = siluf_(acc);
  int h = c >> 8, d = c & 255;
  out[(((size_t)(b * NH + h)) * Ls + l) * 256 + d] = y;
}

// ------- l2norm q,k; kb = kn*beta; vb = v*beta -----------------------------
__global__ __launch_bounds__(256) void prep_qkv(
    const float* __restrict__ q, const float* __restrict__ k,
    const float* __restrict__ v, const float* __restrict__ beta,
    float* __restrict__ qn, float* __restrict__ kn,
    float* __restrict__ kb, float* __restrict__ vb)
{
  int i = blockIdx.x;
  int t = threadIdx.x;
  size_t base = (size_t)i * 256 + t;
  float qv = q[base], kv = k[base], vv = v[base];
  float sq = qv * qv, sk = kv * kv;
#pragma unroll
  for (int off = 32; off; off >>= 1) {
    sq += __shfl_down(sq, off);
    sk += __shfl_down(sk, off);
  }
  __shared__ float rq_[4], rk_[4];
  int w = t >> 6;
  if ((t & 63) == 0) { rq_[w] = sq; rk_[w] = sk; }
  __syncthreads();
  sq = rq_[0] + rq_[1] + rq_[2] + rq_[3];
  sk = rk_[0] + rk_[1] + rk_[2] + rk_[3];
  float rq = rsqrtf(sq + 1e-6f), rk = rsqrtf(sk + 1e-6f);
  float bt = beta[i];
  qn[base] = qv * rq;
  kn[base] = kv * rk;
  kb[base] = kv * rk * bt;
  vb[base] = vv * bt;
}

// ------- per (b,h,chunk): A, T=inv(I+A), attn, u=T@vb; emit bf16 w/q/knT ---
__global__ __launch_bounds__(256) void chunk_prep(
    const float* __restrict__ kb, const float* __restrict__ kn,
    const float* __restrict__ qn, const float* __restrict__ vb,
    float* __restrict__ attn_g, float* __restrict__ u_out,
    ushort_t* __restrict__ wn_bf, ushort_t* __restrict__ q_bf,
    ushort_t* __restrict__ knT_bf)
{
  __shared__ float kbs[32][260], kns[32][260], bufs[32][260];
  __shared__ float Am[32][33], Tm[32][33];
  int t = threadIdx.x;
  int cc = blockIdx.x & 63, bh = blockIdx.x >> 6;
  size_t gbase = ((size_t)bh * Ls + cc * 32) * 256;
#pragma unroll
  for (int r = 0; r < 8; ++r) {
    int s = r * 256 + t; int row = s >> 6, c4 = (s & 63) * 4;
    *(float4*)&kbs[row][c4]  = *(const float4*)(kb + gbase + row * 256 + c4);
    *(float4*)&kns[row][c4]  = *(const float4*)(kn + gbase + row * 256 + c4);
    *(float4*)&bufs[row][c4] = *(const float4*)(qn + gbase + row * 256 + c4);
  }
  __syncthreads();
  float* ag = attn_g + ((size_t)bh * 64 + cc) * 1024;
#pragma unroll
  for (int p = 0; p < 4; ++p) {
    int pair = p * 256 + t, i = pair >> 5, j = pair & 31;
    float aA = 0.f, aQ = 0.f;
#pragma unroll 8
    for (int kk = 0; kk < 256; kk += 4) {
      float4 kf = *(float4*)&kns[j][kk];
      float4 bfv = *(float4*)&kbs[i][kk];
      float4 qf = *(float4*)&bufs[i][kk];
      aA += dot4(bfv, kf);
      aQ += dot4(qf, kf);
    }
    Am[i][j] = (j < i) ? aA : 0.f;
    ag[i * 32 + j] = (j <= i) ? aQ : 0.f;
  }
  __syncthreads();
  if (t < 32) {
    for (int i2 = 0; i2 < 32; ++i2) Tm[i2][t] = (i2 == t) ? 1.f : 0.f;
  }
  __syncthreads();
  for (int i2 = 1; i2 < 32; ++i2) {
    if (t < i2) {
      float s = 0.f;
      for (int m2 = t; m2 < i2; ++m2) s = fmaf(Am[i2][m2], Tm[m2][t], s);
      Tm[i2][t] = -s;
    }
    __syncthreads();
  }
  // emit q_bf (from bufs, still holding qn) and knT_bf (from kns)
#pragma unroll
  for (int r = 0; r < 8; ++r) {
    int s = r * 256 + t; int row = s >> 6, c4 = (s & 63) * 4;
    float4 qv = *(float4*)&bufs[row][c4];
    ushort4 qb; ushort_t* qq = (ushort_t*)&qb;
    qq[0] = f2bf(qv.x); qq[1] = f2bf(qv.y); qq[2] = f2bf(qv.z); qq[3] = f2bf(qv.w);
    *(ushort4*)(q_bf + gbase + row * 256 + c4) = qb;
  }
  {
    u32 pk[16];
#pragma unroll
    for (int j = 0; j < 16; ++j) {
      ushort_t e0 = f2bf(kns[2 * j][t]);
      ushort_t e1 = f2bf(kns[2 * j + 1][t]);
      pk[j] = (u32)e0 | ((u32)e1 << 16);
    }
    ushort_t* kout = knT_bf + gbase + (size_t)t * 32;   // [bh][cc][256][32]
#pragma unroll
    for (int q2 = 0; q2 < 4; ++q2)
      *(uint4*)(kout + q2 * 8) = *(uint4*)&pk[q2 * 4];
  }
  __syncthreads();   // bufs reads done before overwrite
#pragma unroll
  for (int r = 0; r < 8; ++r) {
    int s = r * 256 + t; int row = s >> 6, c4 = (s & 63) * 4;
    *(float4*)&bufs[row][c4] = *(const float4*)(vb + gbase + row * 256 + c4);
  }
  __syncthreads();
  int d4 = (t & 63) * 4, i8 = (t >> 6) * 8;
#pragma unroll
  for (int r = 0; r < 8; ++r) {
    int i = i8 + r;
    float4 wa = make_float4(0,0,0,0), ua = make_float4(0,0,0,0);
#pragma unroll
    for (int m2 = 0; m2 < 32; ++m2) {
      float tv = Tm[i][m2];
      float4 kbf = *(float4*)&kbs[m2][d4];
      float4 vbf = *(float4*)&bufs[m2][d4];
      wa.x = fmaf(tv, kbf.x, wa.x); wa.y = fmaf(tv, kbf.y, wa.y);
      wa.z = fmaf(tv, kbf.z, wa.z); wa.w = fmaf(tv, kbf.w, wa.w);
      ua.x = fmaf(tv, vbf.x, ua.x); ua.y = fmaf(tv, vbf.y, ua.y);
      ua.z = fmaf(tv, vbf.z, ua.z); ua.w = fmaf(tv, vbf.w, ua.w);
    }
    ushort4 wb; ushort_t* wwp = (ushort_t*)&wb;
    wwp[0] = f2bf(-wa.x); wwp[1] = f2bf(-wa.y); wwp[2] = f2bf(-wa.z); wwp[3] = f2bf(-wa.w);
    *(ushort4*)(wn_bf + gbase + i * 256 + d4) = wb;
    *(float4*)(u_out + gbase + i * 256 + d4) = ua;
  }
}

// ------- MFMA serial chunk scan -------------------------------------------
// 128 blocks = 8 bh x 16 dv-groups (16 cols). 4 waves:
//   wv0: u2 rows 0-15, wv1: u2 rows 16-31, wv2: o1 rows 0-15, wv3: o1 16-31.
// S[256dk x 16dv] in f32 accumulators (4 dk-tiles per wave, never rounded);
// split-bf16 copy in LDS per chunk as B-operand; u2 split likewise.
__global__ __launch_bounds__(256) void delta_chain_mfma(
    const ushort_t* __restrict__ wn_bf, const ushort_t* __restrict__ q_bf,
    const ushort_t* __restrict__ knT_bf, float* __restrict__ u_g,
    float* __restrict__ o1_g)
{
  __shared__ ushort_t Shi[16][264];
  __shared__ ushort_t Slo[16][264];
  __shared__ float u2L[32][17];
  int t = threadIdx.x;
  int g = blockIdx.x & 15, bh = blockIdx.x >> 4;
  int b = bh >> 2, h = bh & 3;
  int wv = t >> 6, lane = t & 63;
  int lquad = lane >> 4, l16 = lane & 15;
  int j0 = g * 16;
  const ushort_t* wp = wn_bf + (size_t)bh * Ls * 256;
  const ushort_t* qp = q_bf  + (size_t)bh * Ls * 256;
  const ushort_t* kp = knT_bf + (size_t)bh * Ls * 256;
  float* up = u_g + (size_t)bh * Ls * 256;
  int Mt = wv & 1;
  bool isU = (wv < 2);
  floatx4 Sacc[4];
#pragma unroll
  for (int i = 0; i < 4; ++i)
#pragma unroll
    for (int r = 0; r < 4; ++r) Sacc[i][r] = 0.f;
  {
    u32* z1 = (u32*)&Shi[0][0];
    u32* z2 = (u32*)&Slo[0][0];
    for (int i = t; i < 2112; i += 256) { z1[i] = 0; z2[i] = 0; }
  }
  __syncthreads();
  int arow = (Mt * 16 + l16) * 256;
  for (int cc = 0; cc < NCh; ++cc) {
    size_t cb = (size_t)cc * 8192;
    floatx4 acc;
    if (isU) {
#pragma unroll
      for (int r = 0; r < 4; ++r)
        acc[r] = up[cb + (size_t)(Mt * 16 + lquad * 4 + r) * 256 + j0 + l16];
    } else {
#pragma unroll
      for (int r = 0; r < 4; ++r) acc[r] = 0.f;
    }
    const ushort_t* ap = (isU ? wp : qp) + cb + arow;
#pragma unroll
    for (int ks = 0; ks < 8; ++ks) {
      short8 afr = *(const short8*)(ap + ks * 32 + lquad * 8);
      short8 sh  = *(const short8*)&Shi[l16][ks * 32 + lquad * 8];
      short8 sl  = *(const short8*)&Slo[l16][ks * 32 + lquad * 8];
      acc = __builtin_amdgcn_mfma_f32_16x16x32_bf16(afr, sh, acc, 0, 0, 0);
      acc = __builtin_amdgcn_mfma_f32_16x16x32_bf16(afr, sl, acc, 0, 0, 0);
    }
    if (isU) {
#pragma unroll
      for (int r = 0; r < 4; ++r) {
        int row = Mt * 16 + lquad * 4 + r;
        u2L[row][l16] = acc[r];
        up[cb + (size_t)row * 256 + j0 + l16] = acc[r];   // persist u2
      }
    } else {
#pragma unroll
      for (int r = 0; r < 4; ++r) {
        int l = cc * 32 + Mt * 16 + lquad * 4 + r;
        o1_g[(((size_t)b * Ls + l) * NH + h) * 256 + j0 + l16] = acc[r];
      }
    }
    __syncthreads();   // u2L ready; Shi/Slo reads of this chunk complete
    short8 uh, ul;
#pragma unroll
    for (int j = 0; j < 8; ++j) {
      float f = u2L[lquad * 8 + j][l16];
      ushort_t hi = f2bf(f);
      uh[j] = (short)hi;
      ul[j] = (short)f2bf(f - bf2f(hi));
    }
    const ushort_t* kcc = kp + cb;
#pragma unroll
    for (int i = 0; i < 4; ++i) {
      short8 kfr = *(const short8*)(kcc + (size_t)((wv * 4 + i) * 16 + l16) * 32 + lquad * 8);
      Sacc[i] = __builtin_amdgcn_mfma_f32_16x16x32_bf16(kfr, uh, Sacc[i], 0, 0, 0);
      Sacc[i] = __builtin_amdgcn_mfma_f32_16x16x32_bf16(kfr, ul, Sacc[i], 0, 0, 0);
    }
#pragma unroll
    for (int i = 0; i < 4; ++i) {
      int dk0 = (wv * 4 + i) * 16 + lquad * 4;
      ushort4 h4, l4;
      ushort_t* hp = (ushort_t*)&h4;
      ushort_t* lp = (ushort_t*)&l4;
#pragma unroll
      for (int r = 0; r < 4; ++r) {
        float sv = Sacc[i][r];
        ushort_t hi = f2bf(sv);
        hp[r] = hi;
        lp[r] = f2bf(sv - bf2f(hi));
      }
      *(ushort4*)&Shi[l16][dk0] = h4;
      *(ushort4*)&Slo[l16][dk0] = l4;
    }
    __syncthreads();   // S copy ready for next chunk
  }
}

// ------- delta += attn @ u2 ------------------------------------------------
__global__ __launch_bounds__(256) void delta_attn_add(
    const float* __restrict__ attn_g, const float* __restrict__ u2_g,
    float* __restrict__ delta)
{
  __shared__ float u2s[32][260];
  __shared__ float at[32][36];
  int t = threadIdx.x;
  int cc = blockIdx.x & 63, bh = blockIdx.x >> 6;
  int b = bh >> 2, h = bh & 3;
  size_t gbase = ((size_t)bh * Ls + cc * 32) * 256;
#pragma unroll
  for (int r = 0; r < 8; ++r) {
    int s = r * 256 + t; int row = s >> 6, c4 = (s & 63) * 4;
    *(float4*)&u2s[row][c4] = *(const float4*)(u2_g + gbase + row * 256 + c4);
  }
  *(float4*)&at[t >> 3][(t & 7) * 4] =
      *(const float4*)(attn_g + ((size_t)bh * 64 + cc) * 1024 + t * 4);
  __syncthreads();
  int d4 = (t & 63) * 4, i8 = (t >> 6) * 8;
#pragma unroll
  for (int r = 0; r < 8; ++r) {
    int i = i8 + r;
    int l = cc * 32 + i;
    size_t ob = (((size_t)b * Ls + l) * NH + h) * 256 + d4;
    float4 acc = *(float4*)(delta + ob);
#pragma unroll
    for (int m = 0; m < 32; ++m) {
      float av = at[i][m];
      float4 uf = *(float4*)&u2s[m][d4];
      acc.x = fmaf(av, uf.x, acc.x); acc.y = fmaf(av, uf.y, acc.y);
      acc.z = fmaf(av, uf.z, acc.z); acc.w = fmaf(av, uf.w, acc.w);
    }
    *(float4*)(delta + ob) = acc;
  }
}

// ------- FIR 63-tap + 3-tap causal depthwise over v ------------------------
__global__ __launch_bounds__(256) void fir_conv(
    const float* __restrict__ v, const float* __restrict__ wlg,
    const float* __restrict__ wsg, float* __restrict__ firl,
    float* __restrict__ firs)
{
  __shared__ float vt[256][71];
  int t = threadIdx.x;
  int lt = blockIdx.x & 255;
  int bh = blockIdx.x >> 8;
  int b = bh >> 2, h = bh & 3;
  int l0 = lt * 8;
  const float* vp = v + (size_t)bh * Ls * 256;
  for (int r = 0; r < 70; ++r) {
    int ls = l0 - 62 + r;
    vt[t][r] = (ls >= 0) ? vp[(size_t)ls * 256 + t] : 0.f;
  }
  float TL[63], TS3[3];
#pragma unroll
  for (int j = 0; j < 63; ++j) TL[j] = wlg[((size_t)h * 256 + t) * 63 + j];
#pragma unroll
  for (int j = 0; j < 3; ++j) TS3[j] = wsg[((size_t)h * 256 + t) * 3 + j];
  __syncthreads();
  float aL[8] = {0,0,0,0,0,0,0,0}, aS[8] = {0,0,0,0,0,0,0,0};
#pragma unroll
  for (int r = 0; r < 70; ++r) {
    float vm = vt[t][r];
#pragma unroll
    for (int p = 0; p < 8; ++p) {
      int jl = r - p;
      if (jl >= 0 && jl < 63) aL[p] = fmaf(vm, TL[jl], aL[p]);
      int jssrc = r - 60 - p;
      if (jssrc >= 0 && jssrc < 3) aS[p] = fmaf(vm, TS3[jssrc], aS[p]);
    }
  }
#pragma unroll
  for (int p = 0; p < 8; ++p) {
    int l = l0 + p;
    size_t ob = (((size_t)b * Ls + l) * NH + h) * 256 + t;
    firl[ob] = aL[p];
    firs[ob] = aS[p];
  }
}

// ------- gate_in (bf16) ----------------------------------------------------
__global__ __launch_bounds__(256) void build_gate_in_bf(
    const float* __restrict__ x, const float* __restrict__ firs,
    const float* __restrict__ firl, const float* __restrict__ delta,
    const float* __restrict__ v, ushort_t* __restrict__ gin)
{
  int mtok = blockIdx.x, t = threadIdx.x;
  int b = mtok >> 11, l = mtok & 2047;
  float4 xv = *(const float4*)(x + (size_t)mtok * 1024 + t * 4);
  ushort4 xo = make_ushort4(f2bf(xv.x), f2bf(xv.y), f2bf(xv.z), f2bf(xv.w));
  *(ushort4*)(gin + (size_t)mtok * 1056 + t * 4) = xo;
  int w = t >> 6, lane = t & 63;
  for (int br = 0; br < 4; ++br) {
    float s = 0.f, s2 = 0.f;
#pragma unroll
    for (int r = 0; r < 4; ++r) {
      int d = lane + r * 64;
      float val;
      if (br == 0)      val = firs [(size_t)mtok * 1024 + w * 256 + d];
      else if (br == 1) val = firl [(size_t)mtok * 1024 + w * 256 + d];
      else if (br == 2) val = delta[(size_t)mtok * 1024 + w * 256 + d];
      else              val = v[(((size_t)(b * NH + w)) * Ls + l) * 256 + d];
      s += val; s2 = fmaf(val, val, s2);
    }
#pragma unroll
    for (int off = 32; off; off >>= 1) {
      s += __shfl_down(s, off);
      s2 += __shfl_down(s2, off);
    }
    if (lane == 0) {
      float mean = s * (1.f / 256.f);
      float var = s2 * (1.f / 256.f) - mean * mean;
      gin[(size_t)mtok * 1056 + 1024 + br * 8 + w] = f2bf(mean);
      gin[(size_t)mtok * 1056 + 1024 + br * 8 + 4 + w] = f2bf(sqrtf(fmaxf(var, 1e-6f)));
    }
  }
}

// ------- logits -> gates ---------------------------------------------------
__global__ __launch_bounds__(256) void mlp2_gates(
    const float* __restrict__ mh, const float* __restrict__ W2,
    const float* __restrict__ b2, const float* __restrict__ glt,
    float* __restrict__ gates)
{
  int mtok = blockIdx.x, t = threadIdx.x;
  float p[16];
#pragma unroll
  for (int j = 0; j < 16; ++j) p[j] = 0.f;
  for (int k = t; k < 2048; k += 256) {
    float hv = mh[(size_t)mtok * 2048 + k];
    const float* wr = W2 + (size_t)k * 16;
#pragma unroll
    for (int j4 = 0; j4 < 4; ++j4) {
      float4 w4 = *(const float4*)(wr + j4 * 4);
      p[j4*4+0] = fmaf(hv, w4.x, p[j4*4+0]);
      p[j4*4+1] = fmaf(hv, w4.y, p[j4*4+1]);
      p[j4*4+2] = fmaf(hv, w4.z, p[j4*4+2]);
      p[j4*4+3] = fmaf(hv, w4.w, p[j4*4+3]);
    }
  }
#pragma unroll
  for (int j = 0; j < 16; ++j)
#pragma unroll
    for (int off = 32; off; off >>= 1) p[j] += __shfl_down(p[j], off);
  __shared__ float red[4][16];
  __shared__ float zl[16];
  int w = t >> 6;
  if ((t & 63) == 0) {
#pragma unroll
    for (int j = 0; j < 16; ++j) red[w][j] = p[j];
  }
  __syncthreads();
  if (t < 16) {
    float tot = red[0][t] + red[1][t] + red[2][t] + red[3][t] + b2[t];
    float tempv = log1pf(expf(glt[t >> 2])) + 1e-4f;
    zl[t] = tot / tempv;
  }
  __syncthreads();
  if (t < 4) {
    float z0 = zl[t*4], z1 = zl[t*4+1], z2 = zl[t*4+2], z3 = zl[t*4+3];
    float mx = fmaxf(fmaxf(z0, z1), fmaxf(z2, z3));
    float e0 = expf(z0 - mx), e1 = expf(z1 - mx), e2 = expf(z2 - mx), e3 = expf(z3 - mx);
    float inv = 1.f / (e0 + e1 + e2 + e3);
    gates[(size_t)mtok * 16 + t * 4 + 0] = e0 * inv;
    gates[(size_t)mtok * 16 + t * 4 + 1] = e1 * inv;
    gates[(size_t)mtok * 16 + t * 4 + 2] = e2 * inv;
    gates[(size_t)mtok * 16 + t * 4 + 3] = e3 * inv;
  }
}

// ------- o = gated mix, RMSNorm -> bf16 ------------------------------------
__global__ __launch_bounds__(256) void combine_norm_bf(
    const float* __restrict__ firs, const float* __restrict__ firl,
    const float* __restrict__ delta, const float* __restrict__ v,
    const float* __restrict__ gates, const float* __restrict__ onw,
    ushort_t* __restrict__ o)
{
  int mh = blockIdx.x;
  int mtok = mh >> 2, h = mh & 3;
  int t = threadIdx.x;
  int b = mtok >> 11, l = mtok & 2047;
  const float* g = gates + (size_t)mtok * 16 + h * 4;
  float w0 = g[0], w1 = g[1], w2 = g[2], w3 = g[3];
  size_t tb = (size_t)mtok * 1024 + h * 256 + t;
  float val = w0 * firs[tb] + w1 * firl[tb] + w2 * delta[tb]
            + w3 * v[(((size_t)(b * NH + h)) * Ls + l) * 256 + t];
  float s2 = val * val;
#pragma unroll
  for (int off = 32; off; off >>= 1) s2 += __shfl_down(s2, off);
  __shared__ float r4[4];
  if ((t & 63) == 0) r4[t >> 6] = s2;
  __syncthreads();
  float tot = r4[0] + r4[1] + r4[2] + r4[3];
  float rms = rsqrtf(tot * (1.f / 256.f) + 1e-5f);
  o[tb] = f2bf(val * rms * onw[t]);
}

// ---------------------------------------------------------------------------
extern "C" void kernel_launch(void* const* d_in, const int* in_sizes, int n_in,
                              void* d_out, int out_size, void* d_ws, size_t ws_size,
                              hipStream_t stream) {
  const float* x     = (const float*)d_in[0];
  const float* Wq    = (const float*)d_in[1];
  const float* Wk    = (const float*)d_in[2];
  const float* Wv    = (const float*)d_in[3];
  const float* Wb    = (const float*)d_in[4];
  const float* convq = (const float*)d_in[5];
  const float* convk = (const float*)d_in[6];
  const float* convv = (const float*)d_in[7];
  const float* firsw = (const float*)d_in[8];
  const float* firlw = (const float*)d_in[9];
  const float* mlpw1 = (const float*)d_in[10];
  const float* mlpb1 = (const float*)d_in[11];
  const float* mlpw2 = (const float*)d_in[12];
  const float* mlpb2 = (const float*)d_in[13];
  const float* glt   = (const float*)d_in[14];
  const float* onw   = (const float*)d_in[15];
  const float* Wo    = (const float*)d_in[16];
  float* ws = (float*)d_ws;

  ushort_t* x_bf  = (ushort_t*)(ws + off_firs);
  ushort_t* Wq_t  = (ushort_t*)(ws + off_firl);
  ushort_t* Wk_t  = (ushort_t*)(ws + off_firl + 524288);
  ushort_t* Wv_t  = (ushort_t*)(ws + off_firl + 1048576);
  ushort_t* gin_bf= (ushort_t*)(ws + off_gin);
  ushort_t* w1_t  = (ushort_t*)(ws + off_xk);
  ushort_t* o_bf  = (ushort_t*)(ws + off_xv);
  ushort_t* Wo_t  = (ushort_t*)(ws + off_beta);
  // bf16 delta-chain operands (reuse fir regions before fir_conv runs)
  ushort_t* wn_bf  = (ushort_t*)(ws + off_firs);              // 8 MB
  ushort_t* q_bf   = (ushort_t*)(ws + off_firs + 2097152);    // 8 MB
  ushort_t* knT_bf = (ushort_t*)(ws + off_firl);              // 8 MB

  dim3 blk(256);
  // projections (bf16 MFMA) + beta
  to_bf16<<<2048, blk, 0, stream>>>(x, x_bf, 4194304);
  convT<<<dim3(32, 32), blk, 0, stream>>>(Wq, Wq_t, 1024, 1024);
  convT<<<dim3(32, 32), blk, 0, stream>>>(Wk, Wk_t, 1024, 1024);
  convT<<<dim3(32, 32), blk, 0, stream>>>(Wv, Wv_t, 1024, 1024);
  gemm_bf16<<<dim3(8, 32), blk, 0, stream>>>(x_bf, Wq_t, ws + off_xq, 1024, 1024, nullptr, 0);
  gemm_bf16<<<dim3(8, 32), blk, 0, stream>>>(x_bf, Wk_t, ws + off_xk, 1024, 1024, nullptr, 0);
  gemm_bf16<<<dim3(8, 32), blk, 0, stream>>>(x_bf, Wv_t, ws + off_xv, 1024, 1024, nullptr, 0);
  beta_sigmoid<<<4096, blk, 0, stream>>>(x, Wb, ws + off_beta);
  // short causal convs + silu -> head-major q,k,v
  conv4_silu<<<16384, blk, 0, stream>>>(ws + off_xq, convq, ws + off_q);
  conv4_silu<<<16384, blk, 0, stream>>>(ws + off_xk, convk, ws + off_k);
  conv4_silu<<<16384, blk, 0, stream>>>(ws + off_xv, convv, ws + off_v);
  // l2norm + beta products (qn->xq, kn->xk, kb->q, vb->xv)
  prep_qkv<<<16384, blk, 0, stream>>>(ws + off_q, ws + off_k, ws + off_v, ws + off_beta,
                                      ws + off_xq, ws + off_xk, ws + off_q, ws + off_xv);
  // per-chunk T inverse, attn, u (->xv), bf16 {-w, q, knT}
  chunk_prep<<<512, blk, 0, stream>>>(ws + off_q, ws + off_xk, ws + off_xq, ws + off_xv,
                                      ws + off_attn, ws + off_xv, wn_bf, q_bf, knT_bf);
  // serial MFMA scan: u2 over u (xv), o1 -> delta slot (q)
  delta_chain_mfma<<<128, blk, 0, stream>>>(wn_bf, q_bf, knT_bf, ws + off_xv, ws + off_q);
  // delta += attn @ u2
  delta_attn_add<<<512, blk, 0, stream>>>(ws + off_attn, ws + off_xv, ws + off_q);
  // FIR branches (overwrites wn_bf/q_bf/knT_bf regions — dead by now)
  fir_conv<<<2048, blk, 0, stream>>>(ws + off_v, firlw, firsw, ws + off_firl, ws + off_firs);
  // gate input (bf16), MLP1 (MFMA, gelu), gates
  build_gate_in_bf<<<4096, blk, 0, stream>>>(x, ws + off_firs, ws + off_firl, ws + off_q,
                                             ws + off_v, gin_bf);
  convT<<<dim3(64, 33), blk, 0, stream>>>(mlpw1, w1_t, 1056, 2048);
  gemm_bf16<<<dim3(16, 32), blk, 0, stream>>>(gin_bf, w1_t, ws + off_mlph, 2048, 1056, mlpb1, 1);
  mlp2_gates<<<4096, blk, 0, stream>>>(ws + off_mlph, mlpw2, mlpb2, glt, ws + off_gates);
  // combine + RMSNorm -> bf16, output projection (MFMA)
  combine_norm_bf<<<16384, blk, 0, stream>>>(ws + off_firs, ws + off_firl, ws + off_q,
                                             ws + off_v, ws + off_gates, onw, o_bf);
  convT<<<dim3(32, 32), blk, 0, stream>>>(Wo, Wo_t, 1024, 1024);
  gemm_bf16<<<dim3(8, 32), blk, 0, stream>>>(o_bf, Wo_t, (float*)d_out, 1024, 1024, nullptr, 0);
}